// Round 3
// baseline (818.539 us; speedup 1.0000x reference)
//
#include <hip/hip_runtime.h>
#include <math.h>

typedef unsigned long long u64;
typedef unsigned int u32;
typedef unsigned char u8;

#define VOL 1048576              // 64*128*128
#define NTOT 2097152             // 2 batches
#define NWORDS 32768             // NTOT/64
#define RB 1024
#define RT 256
#define PINF 1e30f
#define NINF -1e30f

// ---------------- reduction helper (deterministic) ----------------
__device__ __forceinline__ void block_sum(double v, double* __restrict__ part, int slot, double* sd){
  sd[threadIdx.x] = v;
  __syncthreads();
  for(int s = RT>>1; s>0; s>>=1){
    if((int)threadIdx.x < s) sd[threadIdx.x] += sd[threadIdx.x + s];
    __syncthreads();
  }
  if(threadIdx.x==0) part[(size_t)slot*RB + blockIdx.x] = sd[0];
  __syncthreads();
}

// ---------------- init: prob, bitmasks, dice/ce/conn sums ----------------
__global__ __launch_bounds__(RT) void k_init(const float* __restrict__ net, const int* __restrict__ tgt,
    float* __restrict__ img, u64* __restrict__ ybits, u64* __restrict__ hbits,
    u64* __restrict__ bimg2, double* __restrict__ part)
{
  __shared__ double sd[RT];
  double ce=0, tp=0, spr=0, sy=0, conn=0;
  int g = blockIdx.x*RT + threadIdx.x;
  for(int n=g; n<NTOT; n += RB*RT){
    int b = n >> 20;
    int v = n & (VOL-1);
    const float* nb = net + (size_t)b*(2*VOL);
    float x0 = nb[v], x1 = nb[VOL+v];
    int t = tgt[n];
    int yb = (t>0) ? 1 : 0;
    float p = 1.f/(1.f+expf(x0-x1));
    img[n] = p;
    u64 wy = __ballot(yb);
    u64 wh = __ballot(x1 > x0);
    if((threadIdx.x & 63)==0){
      int wi = n>>6;
      ybits[wi]=wy; hbits[wi]=wh;
      bimg2[wi]=wy; bimg2[NWORDS+wi]=wh;
    }
    float mx = fmaxf(x0,x1);
    float lse = mx + logf(expf(x0-mx)+expf(x1-mx));
    ce += (double)(lse - (yb ? x1 : x0));
    tp += (double)p * yb;
    spr += (double)p;
    sy += (double)yb;
    conn += (double)((int)((x0>0.5f)!=(yb!=0)) + (int)((x1>0.5f)!=(yb!=0)));
  }
  block_sum(ce ,part,0,sd);
  block_sum(tp ,part,1,sd);
  block_sum(spr,part,2,sd);
  block_sum(sy ,part,3,sd);
  block_sum(conn,part,4,sd);
}

// ---------------- fused float soft-skel iteration (z-march, LDS rings) ----------------
// Per dispatch, from img: e1 = erode(img) (or img copy if INIT), e2 = erode(e1),
// open = dilate27(e2), d = relu(e1-open), skel update; writes e1 as new img (loop mode).
#define TX 64
#define TY 8
#define ZC 8
#define IW (TX+6)
#define IH (TY+6)
#define EW (TX+4)
#define EH (TY+4)
#define E2W (TX+2)
#define E2H (TY+2)

template<bool INIT>
__global__ __launch_bounds__(256) void fskel(const float* __restrict__ imgin, float* __restrict__ imgout,
                                             float* __restrict__ skel)
{
  __shared__ float simg[3][IH][IW];
  __shared__ float se1[3][EH][EW];
  __shared__ float se2[E2H][E2W];
  __shared__ float sM[3][TY][TX];
  int bid = blockIdx.x;
  int txb = bid & 1, tyb = (bid>>1)&15, tzb = (bid>>5)&7, b = bid>>8;
  int X0 = txb*TX, Y0 = tyb*TY, z0 = tzb*ZC, z1 = z0+ZC;
  const float* vol = imgin + (size_t)b*VOL;
  float* volo = imgout + (size_t)b*VOL;
  float* skl = skel + (size_t)b*VOL;
  int tid = threadIdx.x;

  for (int s = z0-3; s <= z1+2; ++s){
    { // load img slice s (OOB -> +INF, erode-neutral)
      float* dst = &simg[(s+6)%3][0][0];
      bool zok = (s>=0 && s<64);
      for (int idx=tid; idx<IH*IW; idx+=256){
        int ly = idx/IW, lx = idx-ly*IW;
        int gy = Y0-3+ly, gx = X0-3+lx;
        float v = PINF;
        if (zok && (unsigned)gy<128u && (unsigned)gx<128u)
          v = vol[(s<<14)+(gy<<7)+gx];
        dst[idx] = v;
      }
    }
    __syncthreads();
    int t = s-1;
    if (t >= z0-2){ // e1(t)
      float* dst = &se1[(t+6)%3][0][0];
      const float (*i0)[IW] = simg[(t+5)%3];
      const float (*i1)[IW] = simg[(t+6)%3];
      const float (*i2)[IW] = simg[(t+7)%3];
      bool zok = (t>=0 && t<64);
      for (int idx=tid; idx<EH*EW; idx+=256){
        int ly = idx/EW, lx = idx-ly*EW;
        int gy = Y0-2+ly, gx = X0-2+lx;
        float v = PINF;
        if (zok && (unsigned)gy<128u && (unsigned)gx<128u){
          if (INIT) v = i1[ly+1][lx+1];
          else {
            v = fminf(fminf(i1[ly+1][lx], i1[ly+1][lx+1]), i1[ly+1][lx+2]);
            v = fminf(v, fminf(i1[ly][lx+1], i1[ly+2][lx+1]));
            v = fminf(v, fminf(i0[ly+1][lx+1], i2[ly+1][lx+1]));
          }
        }
        dst[idx] = v;
      }
    }
    __syncthreads();
    int u = s-2;
    if (u >= z0-1){ // e2(u) then Mxy(u)
      const float (*e0)[EW] = se1[(u+5)%3];
      const float (*e1c)[EW] = se1[(u+6)%3];
      const float (*e2s)[EW] = se1[(u+7)%3];
      bool zok = (u>=0 && u<64);
      float* fse2 = &se2[0][0];
      for (int idx=tid; idx<E2H*E2W; idx+=256){
        int ly = idx/E2W, lx = idx-ly*E2W;
        int gy = Y0-1+ly, gx = X0-1+lx;
        float v = NINF; // dilate-neutral at OOB positions
        if (zok && (unsigned)gy<128u && (unsigned)gx<128u){
          v = fminf(fminf(e1c[ly+1][lx], e1c[ly+1][lx+1]), e1c[ly+1][lx+2]);
          v = fminf(v, fminf(e1c[ly][lx+1], e1c[ly+2][lx+1]));
          v = fminf(v, fminf(e0[ly+1][lx+1], e2s[ly+1][lx+1]));
        }
        fse2[idx] = v;
      }
      __syncthreads();
      float* dm = &sM[(u+6)%3][0][0];
      for (int idx=tid; idx<TY*TX; idx+=256){
        int ly = idx/TX, lx = idx-ly*TX;
        float v =            fmaxf(fmaxf(se2[ly  ][lx], se2[ly  ][lx+1]), se2[ly  ][lx+2]);
        v = fmaxf(v, fmaxf(fmaxf(se2[ly+1][lx], se2[ly+1][lx+1]), se2[ly+1][lx+2]));
        v = fmaxf(v, fmaxf(fmaxf(se2[ly+2][lx], se2[ly+2][lx+1]), se2[ly+2][lx+2]));
        dm[idx] = v;
      }
    }
    __syncthreads();
    int z = s-3;
    if (z >= z0){ // output
      const float (*m0)[TX] = sM[(z+5)%3];
      const float (*m1)[TX] = sM[(z+6)%3];
      const float (*m2)[TX] = sM[(z+7)%3];
      const float (*e1r)[EW] = se1[(z+6)%3];
      for (int idx=tid; idx<TY*TX; idx+=256){
        int ly = idx/TX, lx = idx-ly*TX;
        float open_ = fmaxf(fmaxf(m0[ly][lx], m1[ly][lx]), m2[ly][lx]);
        float e1v = e1r[ly+2][lx+2];
        float d = fmaxf(e1v - open_, 0.f);
        int n = (z<<14) + ((Y0+ly)<<7) + (X0+lx);
        if (INIT) skl[n] = d;
        else {
          float so = skl[n];
          skl[n] = so + fmaxf(d - so*d, 0.f);
          volo[n] = e1v;
        }
      }
    }
    __syncthreads();
  }
}

// ---------------- fused binary soft-skel iteration (bit-planes, LDS rings) ----------------
#define ZCB 8
__device__ __forceinline__ u64 berode_x(const u64* P, int tid){
  u64 c = P[tid];
  if (tid & 1) return c & ((c<<1)|(P[tid-1]>>63)) & ((c>>1)|(1ull<<63));
  else         return c & ((c<<1)|1ull) & ((c>>1)|(P[tid+1]<<63));
}
__device__ __forceinline__ u64 bdilate_x(const u64* P, int tid){
  u64 c = P[tid];
  if (tid & 1) return c | (c<<1) | (P[tid-1]>>63) | (c>>1);
  else         return c | (c<<1) | (c>>1) | (P[tid+1]<<63);
}

template<bool INIT>
__global__ __launch_bounds__(256) void bskel(const u64* __restrict__ imgin, u64* __restrict__ imgout,
                                             u64* __restrict__ skel)
{
  __shared__ u64 simg[3][256];
  __shared__ u64 se1[3][256];
  __shared__ u64 se2[256];
  __shared__ u64 sM[3][256];
  int bid = blockIdx.x;
  int tzb = bid & 7, b = (bid>>3)&1, m = bid>>4;
  int z0 = tzb*ZCB, z1 = z0+ZCB;
  size_t base = (size_t)m*NWORDS + (size_t)b*16384;
  const u64* vin = imgin + base;
  u64* vout = imgout + base;
  u64* skl = skel + base;
  int tid = threadIdx.x;
  int y = tid>>1;

  for (int s = z0-3; s <= z1+2; ++s){
    simg[(s+6)%3][tid] = (s>=0 && s<64) ? vin[(s<<8)+tid] : ~0ull;
    __syncthreads();
    int t = s-1;
    if (t >= z0-2){
      u64 r = ~0ull;
      if (t>=0 && t<64){
        const u64* P = simg[(t+6)%3];
        if (INIT) r = P[tid];
        else {
          r = berode_x(P, tid);
          if (y>0)   r &= P[tid-2];
          if (y<127) r &= P[tid+2];
          r &= simg[(t+5)%3][tid];
          r &= simg[(t+7)%3][tid];
        }
      }
      se1[(t+6)%3][tid] = r;
    }
    __syncthreads();
    int u = s-2;
    if (u >= z0-1){
      u64 r = 0;
      if (u>=0 && u<64){
        const u64* P = se1[(u+6)%3];
        r = berode_x(P, tid);
        if (y>0)   r &= P[tid-2];
        if (y<127) r &= P[tid+2];
        r &= se1[(u+5)%3][tid];
        r &= se1[(u+7)%3][tid];
      }
      se2[tid] = r;
      __syncthreads();
      u64 dm = bdilate_x(se2, tid);
      if (y>0)   dm |= bdilate_x(se2, tid-2);
      if (y<127) dm |= bdilate_x(se2, tid+2);
      sM[(u+6)%3][tid] = dm;
    }
    __syncthreads();
    int z = s-3;
    if (z >= z0){
      u64 open_ = sM[(z+5)%3][tid] | sM[(z+6)%3][tid] | sM[(z+7)%3][tid];
      u64 e1v = se1[(z+6)%3][tid];
      u64 d = e1v & ~open_;
      int gw = (z<<8)+tid;
      if (INIT) skl[gw] = d;
      else { skl[gw] |= d; vout[gw] = e1v; }
    }
    __syncthreads();
  }
}

// ---------------- separable Chebyshev EDT: acc = min(16, dist-to-bg) ----------------
// pass X: per-voxel O(1) via 64-bit window + clz/ffs
__global__ __launch_bounds__(256) void edt_px(const u64* __restrict__ yb, const u64* __restrict__ hb,
                                              u8* __restrict__ d)
{
  int g = blockIdx.x*256 + threadIdx.x;   // [0, 2*NTOT)
  int m = g >> 21;
  int n = g & (NTOT-1);
  const u64* bits = m ? hb : yb;
  int x = n & 127;
  int row = n >> 7;
  u64 w0 = bits[row*2], w1 = bits[row*2+1];
  int a = x - 31;
  u64 win;
  if (a < 0)        win = w0 << (-a);
  else if (a == 0)  win = w0;
  else if (a < 64)  win = (w0 >> a) | (w1 << (64-a));
  else              win = w1 >> (a-64);
  if (x < 31)  win |= (1ull << (31-x)) - 1;     // OOB low = fg
  if (x > 95)  win |= (~0ull) << (159-x);      // OOB high = fg
  u64 inv = ~win;
  u64 tl = inv & 0xFFFFFFFFull;   // bits 0..31 = voxels x-31..x
  u64 tr = inv >> 31;             // bit k = voxel x+k
  int dl = tl ? (31 - (63 - __clzll(tl))) : 99;
  int dr = tr ? (__ffsll((unsigned long long)tr) - 1) : 99;
  int dd = min(min(dl, dr), 16);
  d[(size_t)m*NTOT + n] = (u8)dd;
}

// passes Y/Z: d'(v) = min_k max(|k|, d(v+k*STRIDE)), early-exit
template<int STRIDE, int LIM, int SHIFT>
__global__ __launch_bounds__(256) void edt_pyz(const u8* __restrict__ din, u8* __restrict__ dout){
  int g = blockIdx.x*256 + threadIdx.x;
  int m = g >> 21;
  int n = g & (NTOT-1);
  int c = (n >> SHIFT) & (LIM-1);
  size_t idx = (size_t)m*NTOT + n;
  int best = din[idx];
  #pragma unroll 4
  for (int k=1; k<=16; ++k){
    if (best <= k) break;
    int v = 255;
    if (c-k >= 0)  v = din[idx - (size_t)k*STRIDE];
    if (c+k < LIM) v = min(v, (int)din[idx + (size_t)k*STRIDE]);
    best = min(best, max(k, v));
  }
  dout[idx] = (u8)best;
}

// mm: [0..1]=rmaxT(b) [2..3]=rminT(b) [4..5]=rmaxH(b) [6..7]=rminH(b)
__global__ void init_mm(u32* mm){
  int i = threadIdx.x;
  if(i<8) mm[i] = (i==2||i==3||i==6||i==7) ? 0xFFFFFFFFu : 0u;
}

__global__ __launch_bounds__(256) void rminmax(const u64* __restrict__ skel2, const u64* __restrict__ hbits,
                                               const u8* __restrict__ acc, u32* __restrict__ mm){
  int wi = blockIdx.x*256 + threadIdx.x;
  int sel = wi >> 15;
  int li = wi & (NWORDS-1);
  int b = (li>>14)&1;
  u64 s = sel ? (skel2[NWORDS+li] & hbits[li]) : skel2[li];
  const u8* av = acc + (size_t)sel*NTOT + ((size_t)li<<6);
  u32 mx=0, mn=0xFFFFFFFFu;
  for(int i=0;i<64;i++){
    u32 r = ((s>>i)&1ull) ? (u32)av[i] : 0u;
    mx = mx>r?mx:r;
    mn = mn<r?mn:r;
  }
  for(int off=32; off>0; off>>=1){
    u32 omx = (u32)__shfl_down((int)mx, off);
    u32 omn = (u32)__shfl_down((int)mn, off);
    mx = mx>omx?mx:omx;
    mn = mn<omn?mn:omn;
  }
  if((threadIdx.x&63)==0){
    atomicMax(&mm[sel*4+b], mx);
    atomicMin(&mm[sel*4+2+b], mn);
  }
}

// ---------------- fused sobel + final reduce: slots 5..13 ----------------
__global__ __launch_bounds__(RT) void k_tail(const float* __restrict__ net, const float* __restrict__ skelp,
    const u64* __restrict__ ybits, const u64* __restrict__ hbits, const u64* __restrict__ skel2,
    const u8* __restrict__ acc, const u32* __restrict__ mm, double* __restrict__ part)
{
  __shared__ double sd[RT];
  double sob=0, cl1=0,cl2=0,cl3=0,cl4=0,i1=0,un1=0,i2=0,un2=0;
  float rmaxT_[2], rminT_[2], rmaxH_[2], rminH_[2];
  for(int b=0;b<2;b++){
    rmaxT_[b]=fmaxf((float)mm[b],1.f);   rminT_[b]=fmaxf((float)mm[2+b],1.f);
    rmaxH_[b]=fmaxf((float)mm[4+b],1.f); rminH_[b]=fmaxf((float)mm[6+b],1.f);
  }
  const int SMi[3]={1,2,1}, DVi[3]={-1,0,1};
  int g = blockIdx.x*RT + threadIdx.x;
  for(int n=g; n<NTOT; n+=RB*RT){
    int b=n>>20, v=n&(VOL-1);
    int x=n&127, y=(n>>7)&127, z=(n>>14)&63;
    const float* P = net + (size_t)b*(2*VOL);
    // ---- sobel (separable along x; T gradients integer from ybits) ----
    float gpx=0,gpy=0,gpz=0;
    int gtx=0,gty=0,gtz=0;
    #pragma unroll
    for(int da=0;da<3;da++){
      int zz=z+da-1; if((unsigned)zz>=64u) continue;
      #pragma unroll
      for(int db=0;db<3;db++){
        int yy=y+db-1; if((unsigned)yy>=128u) continue;
        int rowv = (zz<<14)+(yy<<7)+x;
        float p0 = (x>0)?   P[rowv-1] : 0.f;
        float p1 = P[rowv];
        float p2 = (x<127)? P[rowv+1] : 0.f;
        float ep = p2-p0, sp = p0+2.f*p1+p2;
        gpx += (float)SMi[db]*ep;
        gpy += (float)SMi[da]*ep;
        gpz += (float)DVi[da]*sp;
        int nv = (b<<20)+rowv;
        int wi = nv>>6, bit = nv&63;
        u64 w = ybits[wi];
        int b1 = (int)((w>>bit)&1ull);
        int bm = 0, bp = 0;
        if (x>0)   bm = (bit==0)  ? (int)((ybits[wi-1]>>63)&1ull) : (int)((w>>(bit-1))&1ull);
        if (x<127) bp = (bit==63) ? (int)( ybits[wi+1]      &1ull) : (int)((w>>(bit+1))&1ull);
        int et = bp-bm, st = bm+2*b1+bp;
        gtx += SMi[db]*et;
        gty += SMi[da]*et;
        gtz += DVi[da]*st;
      }
    }
    float fgtx=(float)gtx, fgty=(float)gty, fgtz=(float)gtz;
    float np_=sqrtf(gpx*gpx+gpy*gpy+gpz*gpz);
    float nt_=sqrtf(fgtx*fgtx+fgty*fgty+fgtz*fgtz);
    float ip=1.f/fmaxf(np_,1e-12f), it=1.f/fmaxf(nt_,1e-12f);
    float num=(gpx*fgtx+gpy*fgty+gpz*fgtz)*ip*it;
    float den=fmaxf((np_*ip)*(nt_*it),1e-8f);
    sob += (double)(num/den);
    // ---- final sums ----
    int wi0 = n>>6, bit0 = n&63;
    int yb = (int)((ybits[wi0]>>bit0)&1ull);
    int hd = (int)((hbits[wi0]>>bit0)&1ull);
    int sT = (int)((skel2[wi0]>>bit0)&1ull);
    int sH = (int)((skel2[NWORDS+wi0]>>bit0)&1ull);
    float dT = (float)acc[n];
    float dH = (float)acc[NTOT+n];
    float x0=P[v], x1=P[VOL+v];
    float p = 1.f/(1.f+expf(x0-x1));
    float sk = skelp[n];
    cl1 += (double)sk * yb;
    cl2 += (double)sk;
    cl3 += sT ? (double)p : 0.0;
    cl4 += (double)sT;
    float q_vl = yb ? fminf(dT, rmaxT_[b])/rmaxT_[b] : 0.f;
    float q_sl = 0.f;
    if(sT){ float t = (rmaxT_[b]-dT+rminT_[b])/rmaxT_[b]; q_sl = t*t; }
    float q_vp = fminf(dH, rmaxH_[b])/rmaxH_[b] * p;
    float q_sp = 0.f;
    if(sH & hd){ float t = (rmaxH_[b]-dH+rminH_[b])/rmaxH_[b]; q_sp = t*t*p; }
    i1  += (double)( q_sp * powf(q_sp+1e-4f, 0.7f) * q_vl );
    un1 += (double)( q_sp * (0.1f*q_sp + 0.9f*q_vl) );
    i2  += (double)( q_sl * powf(q_vp+1e-4f, 0.7f) * q_sl );
    un2 += (double)( q_sl * (0.1f*q_vp + 0.9f*q_sl) );
  }
  block_sum(sob,part,5,sd);
  block_sum(cl1,part,6,sd);  block_sum(cl2,part,7,sd);
  block_sum(cl3,part,8,sd);  block_sum(cl4,part,9,sd);
  block_sum(i1 ,part,10,sd); block_sum(un1,part,11,sd);
  block_sum(i2 ,part,12,sd); block_sum(un2,part,13,sd);
}

// ---------------- finalize scalar ----------------
__global__ __launch_bounds__(RT) void k_finalize(const double* __restrict__ part, float* __restrict__ out){
  __shared__ double sd[RT];
  __shared__ double tot[14];
  for(int s=0;s<14;s++){
    double v=0;
    for(int i=threadIdx.x;i<RB;i+=RT) v += part[(size_t)s*RB+i];
    sd[threadIdx.x]=v; __syncthreads();
    for(int k=RT>>1;k>0;k>>=1){ if((int)threadIdx.x<k) sd[threadIdx.x]+=sd[threadIdx.x+k]; __syncthreads(); }
    if(threadIdx.x==0) tot[s]=sd[0];
    __syncthreads();
  }
  if(threadIdx.x==0){
    const double N = (double)NTOT;
    double ce = tot[0]/N;
    double tp=tot[1], fp=tot[2]-tot[1], fn=tot[3]-tot[1];
    double dice = -((2.0*tp+1e-5)/(2.0*tp+fp+fn+1e-5));
    double conn = tot[4]/(2.0*N);
    double dir  = 1.0 - tot[5]/N;
    double tprec = (tot[6]+1.0)/(tot[7]+1.0);
    double tsens = (tot[8]+1.0)/(tot[9]+1.0);
    double cld = 1.0 - 2.0*tprec*tsens/(tprec+tsens);
    double u1 = 1.0 - (tot[10]+1.0)/(tot[11]+1.0);
    double u2 = 1.0 - (tot[12]+1.0)/(tot[13]+1.0);
    out[0] = (float)(dice+ce+cld+dir+conn+u1+u2);
  }
}

extern "C" void kernel_launch(void* const* d_in, const int* in_sizes, int n_in,
                              void* d_out, int out_size, void* d_ws, size_t ws_size,
                              hipStream_t stream)
{
  (void)in_sizes; (void)n_in; (void)out_size; (void)ws_size;
  const float* net = (const float*)d_in[0];
  const int*   tgt = (const int*)d_in[1];
  float* out = (float*)d_out;
  char* w = (char*)d_ws;
  const size_t MB = 1024*1024;
  float* F1 = (float*)(w + 0*MB);          // prob img (ping)
  float* F2 = (float*)(w + 8*MB);          // skel_pred (soft)
  float* F3 = (float*)(w + 16*MB);         // img pong
  u64* ybits = (u64*)(w + 24*MB);          // 256 KB
  u64* hbits = ybits + NWORDS;             // 256 KB
  u64* skel2 = hbits + NWORDS;             // 512 KB: [T][H]
  u64* bping = skel2 + 2*NWORDS;           // 512 KB: [T][H]
  u64* bpong = bping + 2*NWORDS;           // 512 KB
  u8*  dA    = (u8*)(bpong + 2*NWORDS);    // 4 MB
  u8*  dB    = dA + (size_t)2*NTOT;        // 4 MB
  double* part = (double*)(dB + (size_t)2*NTOT);
  u32* mm = (u32*)(part + (size_t)14*RB);

  init_mm<<<1, 64, 0, stream>>>(mm);
  k_init<<<RB, RT, 0, stream>>>(net, tgt, F1, ybits, hbits, bping, part);

  // float soft_skel(prob, 10): 11 fused dispatches
  fskel<true><<<512,256,0,stream>>>(F1, F3, F2);
  {
    float* pi=F1; float* po=F3;
    for(int i=0;i<10;i++){ fskel<false><<<512,256,0,stream>>>(pi,po,F2); float* t=pi; pi=po; po=t; }
  }
  // binary soft_skel for y_true and hard: 11 fused dispatches
  bskel<true><<<32,256,0,stream>>>(bping, bpong, skel2);
  {
    u64* pi=bping; u64* po=bpong;
    for(int i=0;i<10;i++){ bskel<false><<<32,256,0,stream>>>(pi,po,skel2); u64* t=pi; pi=po; po=t; }
  }
  // separable Chebyshev EDT (== 16-iter min-pool accumulation)
  const int GE = (2*NTOT)/256;
  edt_px<<<GE,256,0,stream>>>(ybits, hbits, dA);
  edt_pyz<128,128,7><<<GE,256,0,stream>>>(dA, dB);
  edt_pyz<16384,64,14><<<GE,256,0,stream>>>(dB, dA);

  rminmax<<<(2*NWORDS)/256,256,0,stream>>>(skel2, hbits, dA, mm);
  k_tail<<<RB,RT,0,stream>>>(net, F2, ybits, hbits, skel2, dA, mm, part);
  k_finalize<<<1,RT,0,stream>>>(part, out);
}

// Round 4
// 755.641 us; speedup vs baseline: 1.0832x; 1.0832x over previous
//
#include <hip/hip_runtime.h>
#include <math.h>

typedef unsigned long long u64;
typedef unsigned int u32;
typedef unsigned char u8;

#define VOL 1048576              // 64*128*128
#define NTOT 2097152             // 2 batches
#define NWORDS 32768             // NTOT/64
#define RB 1024
#define RT 256
#define PINF 1e30f
#define NINF -1e30f

// ---------------- reduction helper (deterministic) ----------------
__device__ __forceinline__ void block_sum(double v, double* __restrict__ part, int slot, double* sd){
  sd[threadIdx.x] = v;
  __syncthreads();
  for(int s = RT>>1; s>0; s>>=1){
    if((int)threadIdx.x < s) sd[threadIdx.x] += sd[threadIdx.x + s];
    __syncthreads();
  }
  if(threadIdx.x==0) part[(size_t)slot*RB + blockIdx.x] = sd[0];
  __syncthreads();
}

// ---------------- init: prob, bitmasks, y8, dice/ce/conn sums ----------------
__global__ __launch_bounds__(RT) void k_init(const float* __restrict__ net, const int* __restrict__ tgt,
    float* __restrict__ img, u64* __restrict__ ybits, u64* __restrict__ hbits,
    u64* __restrict__ bimg2, u8* __restrict__ y8, double* __restrict__ part)
{
  __shared__ double sd[RT];
  double ce=0, tp=0, spr=0, sy=0, conn=0;
  int g = blockIdx.x*RT + threadIdx.x;
  for(int n=g; n<NTOT; n += RB*RT){
    int b = n >> 20;
    int v = n & (VOL-1);
    const float* nb = net + (size_t)b*(2*VOL);
    float x0 = nb[v], x1 = nb[VOL+v];
    int t = tgt[n];
    int yb = (t>0) ? 1 : 0;
    float p = 1.f/(1.f+__expf(x0-x1));
    img[n] = p;
    y8[n] = (u8)yb;
    u64 wy = __ballot(yb);
    u64 wh = __ballot(x1 > x0);
    if((threadIdx.x & 63)==0){
      int wi = n>>6;
      ybits[wi]=wy; hbits[wi]=wh;
      bimg2[wi]=wy; bimg2[NWORDS+wi]=wh;
    }
    float mx = fmaxf(x0,x1);
    float lse = mx + __logf(__expf(x0-mx)+__expf(x1-mx));
    ce += (double)(lse - (yb ? x1 : x0));
    tp += (double)p * yb;
    spr += (double)p;
    sy += (double)yb;
    conn += (double)((int)((x0>0.5f)!=(yb!=0)) + (int)((x1>0.5f)!=(yb!=0)));
  }
  block_sum(ce ,part,0,sd);
  block_sum(tp ,part,1,sd);
  block_sum(spr,part,2,sd);
  block_sum(sy ,part,3,sd);
  block_sum(conn,part,4,sd);
}

// ---------------- systolic fused float soft-skel iteration ----------------
// Stage delays: img d0 (ring4), e1 d2 (ring6), e2 d4 (ring2), Mxy d5 (ring4), out d7.
// Every stage reads only previous-step slots -> ONE barrier per step.
#define TX 64
#define TY 8
#define ZC 8
#define IW 70
#define IH 14
#define EW 68
#define EH 12
#define E2W 66
#define E2H 10

template<bool INIT>
__global__ __launch_bounds__(256) void fskel(const float* __restrict__ imgin, float* __restrict__ imgout,
                                             float* __restrict__ skel)
{
  __shared__ float simg[4][IH*IW];
  __shared__ float se1[6][EH*EW];
  __shared__ float se2[2][E2H*E2W];
  __shared__ float sM[4][TY*TX];
  int bid = blockIdx.x;
  int txb = bid & 1, tyb = (bid>>1)&15, tzb = (bid>>5)&7, b = bid>>8;
  int X0 = txb*TX, Y0 = tyb*TY, z0 = tzb*ZC, z1 = z0+ZC;   // z1 exclusive
  const float* vol = imgin + (size_t)b*VOL;
  float* volo = imgout + (size_t)b*VOL;
  float* skl = skel + (size_t)b*VOL;
  int tid = threadIdx.x;

  for (int s = z0-3; s <= z1+6; ++s){
    // Stage A: load img slice s
    if (s <= z1+2){
      float* dst = simg[(s+96)&3];
      for (int idx=tid; idx<IH*IW; idx+=256){
        int ly = idx/IW, lx = idx-ly*IW;
        int gy = Y0-3+ly, gx = X0-3+lx;
        float v = PINF;
        if ((unsigned)s<64u && (unsigned)gy<128u && (unsigned)gx<128u)
          v = vol[(s<<14)+(gy<<7)+gx];
        dst[idx] = v;
      }
    }
    // Stage B: e1 at t = s-2
    {
      int t = s-2;
      if (t >= z0-2 && t <= z1+1){
        float* dst = se1[(t+96)%6];
        const float* i0 = simg[(t-1+96)&3];
        const float* i1 = simg[(t+96)&3];
        const float* i2 = simg[(t+1+96)&3];
        bool zok = ((unsigned)t < 64u);
        for (int idx=tid; idx<EH*EW; idx+=256){
          int ly = idx/EW, lx = idx-ly*EW;
          int gy = Y0-2+ly, gx = X0-2+lx;
          float v = PINF;
          if (zok && (unsigned)gy<128u && (unsigned)gx<128u){
            int c = (ly+1)*IW + (lx+1);
            if (INIT) v = i1[c];
            else {
              v = fminf(fminf(i1[c-1], i1[c]), i1[c+1]);
              v = fminf(v, fminf(i1[c-IW], i1[c+IW]));
              v = fminf(v, fminf(i0[c], i2[c]));
            }
          }
          dst[idx] = v;
        }
      }
    }
    // Stage C: e2 at t = s-4  (NINF at OOB: feeds dilate/max only)
    {
      int t = s-4;
      if (t >= z0-1 && t <= z1){
        float* dst = se2[(t+96)&1];
        const float* e0 = se1[(t-1+96)%6];
        const float* e1c = se1[(t+96)%6];
        const float* e2s = se1[(t+1+96)%6];
        bool zok = ((unsigned)t<64u);
        for (int idx=tid; idx<E2H*E2W; idx+=256){
          int ly = idx/E2W, lx = idx-ly*E2W;
          int gy = Y0-1+ly, gx = X0-1+lx;
          float v = NINF;
          if (zok && (unsigned)gy<128u && (unsigned)gx<128u){
            int c = (ly+1)*EW + (lx+1);
            v = fminf(fminf(e1c[c-1], e1c[c]), e1c[c+1]);
            v = fminf(v, fminf(e1c[c-EW], e1c[c+EW]));
            v = fminf(v, fminf(e0[c], e2s[c]));
          }
          dst[idx] = v;
        }
      }
    }
    // Stage D: Mxy at t = s-5
    {
      int t = s-5;
      if (t >= z0-1 && t <= z1){
        float* dst = sM[(t+96)&3];
        const float* e2p = se2[(t+96)&1];
        for (int idx=tid; idx<TY*TX; idx+=256){
          int ly = idx>>6, lx = idx&63;
          int c = ly*E2W + lx;
          float v =        fmaxf(fmaxf(e2p[c        ], e2p[c+1      ]), e2p[c+2      ]);
          v = fmaxf(v, fmaxf(fmaxf(e2p[c+E2W   ], e2p[c+E2W+1  ]), e2p[c+E2W+2  ]));
          v = fmaxf(v, fmaxf(fmaxf(e2p[c+2*E2W ], e2p[c+2*E2W+1]), e2p[c+2*E2W+2]));
          dst[idx] = v;
        }
      }
    }
    // Stage E: output at z = s-7
    {
      int z = s-7;
      if (z >= z0 && z < z1){
        const float* m0 = sM[(z-1+96)&3];
        const float* m1 = sM[(z+96)&3];
        const float* m2 = sM[(z+1+96)&3];
        const float* e1r = se1[(z+96)%6];
        for (int idx=tid; idx<TY*TX; idx+=256){
          int ly = idx>>6, lx = idx&63;
          float open_ = fmaxf(fmaxf(m0[idx], m1[idx]), m2[idx]);
          float e1v = e1r[(ly+2)*EW + (lx+2)];
          float d = fmaxf(e1v - open_, 0.f);
          int n = (z<<14) + ((Y0+ly)<<7) + (X0+lx);
          if (INIT) skl[n] = d;
          else {
            float so = skl[n];
            skl[n] = so + fmaxf(d - so*d, 0.f);
            volo[n] = e1v;
          }
        }
      }
    }
    __syncthreads();
  }
}

// ---------------- systolic fused binary soft-skel iteration (bit-planes) ----------------
__device__ __forceinline__ u64 berode_x(const u64* P, int tid){
  u64 c = P[tid];
  if (tid & 1) return c & ((c<<1)|(P[tid-1]>>63)) & ((c>>1)|(1ull<<63));
  else         return c & ((c<<1)|1ull) & ((c>>1)|(P[tid+1]<<63));
}
__device__ __forceinline__ u64 bdilate_x(const u64* P, int tid){
  u64 c = P[tid];
  if (tid & 1) return c | (c<<1) | (P[tid-1]>>63) | (c>>1);
  else         return c | (c<<1) | (c>>1) | (P[tid+1]<<63);
}

template<bool INIT>
__global__ __launch_bounds__(256) void bskel(const u64* __restrict__ imgin, u64* __restrict__ imgout,
                                             u64* __restrict__ skel)
{
  __shared__ u64 simg[4][256];
  __shared__ u64 se1[6][256];
  __shared__ u64 se2[2][256];
  __shared__ u64 sM[4][256];
  int bid = blockIdx.x;
  int tzb = bid & 7, b = (bid>>3)&1, m = bid>>4;
  int z0 = tzb*8, z1 = z0+8;
  size_t base = (size_t)m*NWORDS + (size_t)b*16384;
  const u64* vin = imgin + base;
  u64* vout = imgout + base;
  u64* skl = skel + base;
  int tid = threadIdx.x;
  int y = tid>>1;

  for (int s = z0-3; s <= z1+6; ++s){
    if (s <= z1+2)
      simg[(s+96)&3][tid] = ((unsigned)s<64u) ? vin[(s<<8)+tid] : ~0ull;
    { int t = s-2;
      if (t >= z0-2 && t <= z1+1){
        u64 r = ~0ull;
        if ((unsigned)t<64u){
          const u64* P = simg[(t+96)&3];
          if (INIT) r = P[tid];
          else {
            r = berode_x(P, tid);
            if(y>0)   r &= P[tid-2];
            if(y<127) r &= P[tid+2];
            r &= simg[(t-1+96)&3][tid] & simg[(t+1+96)&3][tid];
          }
        }
        se1[(t+96)%6][tid] = r;
      }
    }
    { int t = s-4;
      if (t >= z0-1 && t <= z1){
        u64 r = 0;
        if ((unsigned)t<64u){
          const u64* P = se1[(t+96)%6];
          r = berode_x(P, tid);
          if(y>0)   r &= P[tid-2];
          if(y<127) r &= P[tid+2];
          r &= se1[(t-1+96)%6][tid] & se1[(t+1+96)%6][tid];
        }
        se2[(t+96)&1][tid] = r;
      }
    }
    { int t = s-5;
      if (t >= z0-1 && t <= z1){
        const u64* P = se2[(t+96)&1];
        u64 dm = bdilate_x(P, tid);
        if(y>0)   dm |= bdilate_x(P, tid-2);
        if(y<127) dm |= bdilate_x(P, tid+2);
        sM[(t+96)&3][tid] = dm;
      }
    }
    { int z = s-7;
      if (z >= z0 && z < z1){
        u64 open_ = sM[(z-1+96)&3][tid] | sM[(z+96)&3][tid] | sM[(z+1+96)&3][tid];
        u64 e1v = se1[(z+96)%6][tid];
        u64 d = e1v & ~open_;
        int gw = (z<<8)+tid;
        if (INIT) skl[gw] = d;
        else { skl[gw] |= d; vout[gw] = e1v; }
      }
    }
    __syncthreads();
  }
}

// ---------------- separable Chebyshev EDT: acc = min(16, dist-to-bg) ----------------
__global__ __launch_bounds__(256) void edt_px(const u64* __restrict__ yb, const u64* __restrict__ hb,
                                              u8* __restrict__ d)
{
  int g = blockIdx.x*256 + threadIdx.x;
  int m = g >> 21;
  int n = g & (NTOT-1);
  const u64* bits = m ? hb : yb;
  int x = n & 127;
  int row = n >> 7;
  u64 w0 = bits[row*2], w1 = bits[row*2+1];
  int a = x - 31;
  u64 win;
  if (a < 0)        win = w0 << (-a);
  else if (a == 0)  win = w0;
  else if (a < 64)  win = (w0 >> a) | (w1 << (64-a));
  else              win = w1 >> (a-64);
  if (x < 31)  win |= (1ull << (31-x)) - 1;
  if (x > 95)  win |= (~0ull) << (159-x);
  u64 inv = ~win;
  u64 tl = inv & 0xFFFFFFFFull;
  u64 tr = inv >> 31;
  int dl = tl ? (31 - (63 - __clzll(tl))) : 99;
  int dr = tr ? (__ffsll((unsigned long long)tr) - 1) : 99;
  int dd = min(min(dl, dr), 16);
  d[(size_t)m*NTOT + n] = (u8)dd;
}

template<int STRIDE, int LIM, int SHIFT>
__global__ __launch_bounds__(256) void edt_pyz(const u8* __restrict__ din, u8* __restrict__ dout){
  int g = blockIdx.x*256 + threadIdx.x;
  int m = g >> 21;
  int n = g & (NTOT-1);
  int c = (n >> SHIFT) & (LIM-1);
  size_t idx = (size_t)m*NTOT + n;
  int best = din[idx];
  #pragma unroll 4
  for (int k=1; k<=16; ++k){
    if (best <= k) break;
    int v = 255;
    if (c-k >= 0)  v = din[idx - (size_t)k*STRIDE];
    if (c+k < LIM) v = min(v, (int)din[idx + (size_t)k*STRIDE]);
    best = min(best, max(k, v));
  }
  dout[idx] = (u8)best;
}

__global__ void init_mm(u32* mm){
  int i = threadIdx.x;
  if(i<8) mm[i] = (i==2||i==3||i==6||i==7) ? 0xFFFFFFFFu : 0u;
}

__global__ __launch_bounds__(256) void rminmax(const u64* __restrict__ skel2, const u64* __restrict__ hbits,
                                               const u8* __restrict__ acc, u32* __restrict__ mm){
  int wi = blockIdx.x*256 + threadIdx.x;
  int sel = wi >> 15;
  int li = wi & (NWORDS-1);
  int b = (li>>14)&1;
  u64 s = sel ? (skel2[NWORDS+li] & hbits[li]) : skel2[li];
  const u8* av = acc + (size_t)sel*NTOT + ((size_t)li<<6);
  u32 mx=0, mn=0xFFFFFFFFu;
  for(int i=0;i<64;i++){
    u32 r = ((s>>i)&1ull) ? (u32)av[i] : 0u;
    mx = mx>r?mx:r;
    mn = mn<r?mn:r;
  }
  for(int off=32; off>0; off>>=1){
    u32 omx = (u32)__shfl_down((int)mx, off);
    u32 omn = (u32)__shfl_down((int)mn, off);
    mx = mx>omx?mx:omx;
    mn = mn<omn?mn:omn;
  }
  if((threadIdx.x&63)==0){
    atomicMax(&mm[sel*4+b], mx);
    atomicMin(&mm[sel*4+2+b], mn);
  }
}

// ---------------- fused sobel + final reduce, 4 voxels per thread ----------------
__global__ __launch_bounds__(RT) void k_tail(const float* __restrict__ net, const float* __restrict__ skelp,
    const u64* __restrict__ ybits, const u64* __restrict__ hbits, const u64* __restrict__ skel2,
    const u8* __restrict__ acc, const u8* __restrict__ y8, const u32* __restrict__ mm,
    double* __restrict__ part)
{
  __shared__ double sd[RT];
  double sob=0, cl1=0,cl2=0,cl3=0,cl4=0,i1=0,un1=0,i2=0,un2=0;
  float rmaxT_[2], rminT_[2], rmaxH_[2], rminH_[2];
  for(int b=0;b<2;b++){
    rmaxT_[b]=fmaxf((float)mm[b],1.f);   rminT_[b]=fmaxf((float)mm[2+b],1.f);
    rmaxH_[b]=fmaxf((float)mm[4+b],1.f); rminH_[b]=fmaxf((float)mm[6+b],1.f);
  }
  const int SMi[3]={1,2,1}, DVi[3]={-1,0,1};
  int g = blockIdx.x*RT + threadIdx.x;
  const int NR = NTOT>>2;
  for(int r=g; r<NR; r+=RB*RT){
    int n0 = r<<2;
    int b = n0>>20, v0 = n0&(VOL-1);
    int xb = n0&127, y=(n0>>7)&127, z=(n0>>14)&63;
    const float* P = net + (size_t)b*(2*VOL);
    const u8* Y8 = y8 + ((size_t)b<<20);
    float gpx[4]={0,0,0,0}, gpy[4]={0,0,0,0}, gpz[4]={0,0,0,0};
    int   gtx[4]={0,0,0,0}, gty[4]={0,0,0,0}, gtz[4]={0,0,0,0};
    #pragma unroll
    for(int da=0;da<3;da++){
      int zz=z+da-1; if((unsigned)zz>=64u) continue;
      #pragma unroll
      for(int db=0;db<3;db++){
        int yy=y+db-1; if((unsigned)yy>=128u) continue;
        int rb_ = (zz<<14)+(yy<<7)+xb;
        float pv[6]; int tv[6];
        #pragma unroll
        for(int j=0;j<6;j++){
          int xx = xb-1+j;
          bool ok = (unsigned)xx<128u;
          pv[j] = ok ? P[rb_-1+j] : 0.f;
          tv[j] = ok ? (int)Y8[rb_-1+j] : 0;
        }
        int smb=SMi[db], sma=SMi[da], dva=DVi[da];
        #pragma unroll
        for(int e=0;e<4;e++){
          float ep = pv[e+2]-pv[e], sp = pv[e]+2.f*pv[e+1]+pv[e+2];
          gpx[e] += (float)smb*ep; gpy[e] += (float)sma*ep; gpz[e] += (float)dva*sp;
          int et = tv[e+2]-tv[e], st = tv[e]+2*tv[e+1]+tv[e+2];
          gtx[e] += smb*et; gty[e] += sma*et; gtz[e] += dva*st;
        }
      }
    }
    float4 X0 = *(const float4*)&P[v0];
    float4 X1 = *(const float4*)&P[VOL+v0];
    float4 SK = *(const float4*)&skelp[n0];
    uchar4 DT = *(const uchar4*)&acc[n0];
    uchar4 DH = *(const uchar4*)&acc[NTOT+n0];
    int wi0 = n0>>6, bit0 = n0&63;
    int ybq = (int)((ybits[wi0]>>bit0)&0xFull);
    int hdq = (int)((hbits[wi0]>>bit0)&0xFull);
    int sTq = (int)((skel2[wi0]>>bit0)&0xFull);
    int sHq = (int)((skel2[NWORDS+wi0]>>bit0)&0xFull);
    float fsob=0,fcl1=0,fcl2=0,fcl3=0,fcl4=0,fi1=0,fun1=0,fi2=0,fun2=0;
    #pragma unroll
    for(int e=0;e<4;e++){
      float ftx=(float)gtx[e], fty=(float)gty[e], ftz=(float)gtz[e];
      float np_=sqrtf(gpx[e]*gpx[e]+gpy[e]*gpy[e]+gpz[e]*gpz[e]);
      float nt_=sqrtf(ftx*ftx+fty*fty+ftz*ftz);
      float ip=1.f/fmaxf(np_,1e-12f), it=1.f/fmaxf(nt_,1e-12f);
      float num=(gpx[e]*ftx+gpy[e]*fty+gpz[e]*ftz)*ip*it;
      float den=fmaxf((np_*ip)*(nt_*it),1e-8f);
      fsob += num/den;
      int yb=(ybq>>e)&1, hd=(hdq>>e)&1, sT=(sTq>>e)&1, sH=(sHq>>e)&1;
      float dT=(float)((const u8*)&DT)[e], dH=(float)((const u8*)&DH)[e];
      float x0v=((const float*)&X0)[e], x1v=((const float*)&X1)[e];
      float p = 1.f/(1.f+__expf(x0v-x1v));
      float sk=((const float*)&SK)[e];
      fcl1 += sk*(float)yb;
      fcl2 += sk;
      float q_vl = yb ? fminf(dT,rmaxT_[b])/rmaxT_[b] : 0.f;
      if (sT){
        fcl3 += p; fcl4 += 1.f;
        float t=(rmaxT_[b]-dT+rminT_[b])/rmaxT_[b]; float q_sl=t*t;
        float q_vp = fminf(dH,rmaxH_[b])/rmaxH_[b]*p;
        fi2  += q_sl*__powf(q_vp+1e-4f,0.7f)*q_sl;
        fun2 += q_sl*(0.1f*q_vp+0.9f*q_sl);
      }
      if (sH & hd){
        float t=(rmaxH_[b]-dH+rminH_[b])/rmaxH_[b]; float q_sp=t*t*p;
        fi1  += q_sp*__powf(q_sp+1e-4f,0.7f)*q_vl;
        fun1 += q_sp*(0.1f*q_sp+0.9f*q_vl);
      }
    }
    sob+=fsob; cl1+=fcl1; cl2+=fcl2; cl3+=fcl3; cl4+=fcl4;
    i1+=fi1; un1+=fun1; i2+=fi2; un2+=fun2;
  }
  block_sum(sob,part,5,sd);
  block_sum(cl1,part,6,sd);  block_sum(cl2,part,7,sd);
  block_sum(cl3,part,8,sd);  block_sum(cl4,part,9,sd);
  block_sum(i1 ,part,10,sd); block_sum(un1,part,11,sd);
  block_sum(i2 ,part,12,sd); block_sum(un2,part,13,sd);
}

// ---------------- finalize scalar ----------------
__global__ __launch_bounds__(RT) void k_finalize(const double* __restrict__ part, float* __restrict__ out){
  __shared__ double sd[RT];
  __shared__ double tot[14];
  for(int s=0;s<14;s++){
    double v=0;
    for(int i=threadIdx.x;i<RB;i+=RT) v += part[(size_t)s*RB+i];
    sd[threadIdx.x]=v; __syncthreads();
    for(int k=RT>>1;k>0;k>>=1){ if((int)threadIdx.x<k) sd[threadIdx.x]+=sd[threadIdx.x+k]; __syncthreads(); }
    if(threadIdx.x==0) tot[s]=sd[0];
    __syncthreads();
  }
  if(threadIdx.x==0){
    const double N = (double)NTOT;
    double ce = tot[0]/N;
    double tp=tot[1], fp=tot[2]-tot[1], fn=tot[3]-tot[1];
    double dice = -((2.0*tp+1e-5)/(2.0*tp+fp+fn+1e-5));
    double conn = tot[4]/(2.0*N);
    double dir  = 1.0 - tot[5]/N;
    double tprec = (tot[6]+1.0)/(tot[7]+1.0);
    double tsens = (tot[8]+1.0)/(tot[9]+1.0);
    double cld = 1.0 - 2.0*tprec*tsens/(tprec+tsens);
    double u1 = 1.0 - (tot[10]+1.0)/(tot[11]+1.0);
    double u2 = 1.0 - (tot[12]+1.0)/(tot[13]+1.0);
    out[0] = (float)(dice+ce+cld+dir+conn+u1+u2);
  }
}

extern "C" void kernel_launch(void* const* d_in, const int* in_sizes, int n_in,
                              void* d_out, int out_size, void* d_ws, size_t ws_size,
                              hipStream_t stream)
{
  (void)in_sizes; (void)n_in; (void)out_size; (void)ws_size;
  const float* net = (const float*)d_in[0];
  const int*   tgt = (const int*)d_in[1];
  float* out = (float*)d_out;
  char* w = (char*)d_ws;
  const size_t MB = 1024*1024;
  float* F1 = (float*)(w + 0*MB);          // prob img (ping)
  float* F2 = (float*)(w + 8*MB);          // skel_pred (soft)
  float* F3 = (float*)(w + 16*MB);         // img pong
  u64* ybits = (u64*)(w + 24*MB);
  u64* hbits = ybits + NWORDS;
  u64* skel2 = hbits + NWORDS;             // [T][H]
  u64* bping = skel2 + 2*NWORDS;           // [T][H]
  u64* bpong = bping + 2*NWORDS;
  u8*  dA    = (u8*)(bpong + 2*NWORDS);    // 4 MB
  u8*  dB    = dA + (size_t)2*NTOT;        // 4 MB
  u8*  y8    = dB + (size_t)2*NTOT;        // 2 MB
  double* part = (double*)(y8 + (size_t)NTOT);
  u32* mm = (u32*)(part + (size_t)14*RB);

  init_mm<<<1, 64, 0, stream>>>(mm);
  k_init<<<RB, RT, 0, stream>>>(net, tgt, F1, ybits, hbits, bping, y8, part);

  // float soft_skel(prob, 10): 11 systolic dispatches
  fskel<true><<<512,256,0,stream>>>(F1, F3, F2);
  {
    float* pi=F1; float* po=F3;
    for(int i=0;i<10;i++){ fskel<false><<<512,256,0,stream>>>(pi,po,F2); float* t=pi; pi=po; po=t; }
  }
  // binary soft_skel for y_true and hard: 11 systolic dispatches
  bskel<true><<<32,256,0,stream>>>(bping, bpong, skel2);
  {
    u64* pi=bping; u64* po=bpong;
    for(int i=0;i<10;i++){ bskel<false><<<32,256,0,stream>>>(pi,po,skel2); u64* t=pi; pi=po; po=t; }
  }
  // separable Chebyshev EDT
  const int GE = (2*NTOT)/256;
  edt_px<<<GE,256,0,stream>>>(ybits, hbits, dA);
  edt_pyz<128,128,7><<<GE,256,0,stream>>>(dA, dB);
  edt_pyz<16384,64,14><<<GE,256,0,stream>>>(dB, dA);

  rminmax<<<(2*NWORDS)/256,256,0,stream>>>(skel2, hbits, dA, mm);
  k_tail<<<RB,RT,0,stream>>>(net, F2, ybits, hbits, skel2, dA, y8, mm, part);
  k_finalize<<<1,RT,0,stream>>>(part, out);
}

// Round 5
// 620.955 us; speedup vs baseline: 1.3182x; 1.2169x over previous
//
#include <hip/hip_runtime.h>
#include <math.h>

typedef unsigned long long u64;
typedef unsigned int u32;
typedef unsigned char u8;

#define VOL 1048576              // 64*128*128
#define NTOT 2097152             // 2 batches
#define NWORDS 32768             // NTOT/64
#define PC0 8192                 // k_init blocks / partial stride
#define PC1 2048                 // k_tail blocks / partial stride
#define PINF 1e30f
#define NINF -1e30f

// ---------------- wave reduction helper ----------------
__device__ __forceinline__ double wred(double v){
  #pragma unroll
  for(int o=32;o;o>>=1) v += __shfl_down(v, o);
  return v;
}

// ---------------- init: prob, bitmasks, y8, dice/ce/conn sums ----------------
__global__ __launch_bounds__(256) void k_init(const float* __restrict__ net, const int* __restrict__ tgt,
    float* __restrict__ img, u64* __restrict__ ybits, u64* __restrict__ hbits,
    u64* __restrict__ bimg2, u8* __restrict__ y8, double* __restrict__ part)
{
  int n = blockIdx.x*256 + threadIdx.x;   // exactly NTOT threads
  int b = n >> 20;
  int v = n & (VOL-1);
  const float* nb = net + (size_t)b*(2*VOL);
  float x0 = nb[v], x1 = nb[VOL+v];
  int t = tgt[n];
  int yb = (t>0) ? 1 : 0;
  float p = 1.f/(1.f+__expf(x0-x1));
  img[n] = p;
  y8[n] = (u8)yb;
  u64 wy = __ballot(yb);
  u64 wh = __ballot(x1 > x0);
  if((threadIdx.x & 63)==0){
    int wi = n>>6;
    ybits[wi]=wy; hbits[wi]=wh;
    bimg2[wi]=wy; bimg2[NWORDS+wi]=wh;
  }
  float mx = fmaxf(x0,x1);
  float lse = mx + __logf(__expf(x0-mx)+__expf(x1-mx));
  double ce = (double)(lse - (yb ? x1 : x0));
  double tp = (double)p * yb;
  double spr = (double)p;
  double sy = (double)yb;
  double conn = (double)((int)((x0>0.5f)!=(yb!=0)) + (int)((x1>0.5f)!=(yb!=0)));
  __shared__ double sw[5][4];
  int wid = threadIdx.x>>6, lane = threadIdx.x&63;
  double vals[5] = {ce,tp,spr,sy,conn};
  #pragma unroll
  for(int s=0;s<5;s++){ double r = wred(vals[s]); if(lane==0) sw[s][wid]=r; }
  __syncthreads();
  if(threadIdx.x==0){
    #pragma unroll
    for(int s=0;s<5;s++) part[(size_t)s*PC0 + blockIdx.x] = sw[s][0]+sw[s][1]+sw[s][2]+sw[s][3];
  }
}

// ---------------- tile-fused float soft-skel step k ----------------
// E-chain: per dispatch: load E_k (20^3 halo), E_{k+1}=erode(E_k) (18^3),
// write E_{k+1} center, open=dilate27(E_{k+1}) via 3-pass, skel update.
template<bool INIT>
__global__ __launch_bounds__(256) void fskel(const float* __restrict__ imgin, float* __restrict__ imgout,
                                             float* __restrict__ skel)
{
  __shared__ float bufA[8000];   // E_k 20^3, reused as B1 [18][18][16]
  __shared__ float bufB[5832];   // E_{k+1} 18^3, reused as B2 [18][16][16]
  int bid = blockIdx.x;
  int xb = bid&7, yb=(bid>>3)&7, zb=(bid>>6)&3, b=bid>>8;
  int X0=xb*16, Y0=yb*16, Z0=zb*16;
  const float* vol = imgin + (size_t)b*VOL;
  float* volo = imgout + (size_t)b*VOL;
  float* skl = skel + (size_t)b*VOL;
  int tid = threadIdx.x;
  // P0: load E_k 20^3 (OOB -> +INF, erode-neutral)
  for (int idx=tid; idx<8000; idx+=256){
    int zz = idx/400; int rem = idx-zz*400; int yy=rem/20; int xx=rem-yy*20;
    int gz=Z0-2+zz, gy=Y0-2+yy, gx=X0-2+xx;
    float v=PINF;
    if((unsigned)gz<64u && (unsigned)gy<128u && (unsigned)gx<128u)
      v = vol[(gz<<14)+(gy<<7)+gx];
    bufA[idx]=v;
  }
  __syncthreads();
  // P1: E_{k+1} = erode7(E_k) on 18^3 (OOB position -> -INF, dilate-neutral)
  for (int idx=tid; idx<5832; idx+=256){
    int zz=idx/324; int rem=idx-zz*324; int yy=rem/18; int xx=rem-yy*18;
    int gz=Z0-1+zz, gy=Y0-1+yy, gx=X0-1+xx;
    float v=NINF;
    if((unsigned)gz<64u && (unsigned)gy<128u && (unsigned)gx<128u){
      int c=(zz+1)*400+(yy+1)*20+(xx+1);
      v = fminf(fminf(bufA[c-1],bufA[c]),bufA[c+1]);
      v = fminf(v, fminf(bufA[c-20],bufA[c+20]));
      v = fminf(v, fminf(bufA[c-400],bufA[c+400]));
    }
    bufB[idx]=v;
  }
  __syncthreads();
  // P2: snapshot E_k center to regs; write E_{k+1} center to global
  int yy0 = (tid>>4)&15, xx0 = tid&15;
  float ek[16];
  #pragma unroll
  for(int j=0;j<16;j++){
    ek[j] = bufA[(j+2)*400+(yy0+2)*20+(xx0+2)];
    int n = ((Z0+j)<<14)+((Y0+yy0)<<7)+(X0+xx0);
    volo[n] = bufB[(j+1)*324+(yy0+1)*18+(xx0+1)];
  }
  __syncthreads();
  // P3: B1[z18][y18][x16] = xmax(bufB) -> bufA
  for (int idx=tid; idx<5184; idx+=256){
    int zz=idx/288; int rem=idx-zz*288; int yy=rem>>4; int xx=rem&15;
    int c = zz*324+yy*18+xx;
    bufA[idx] = fmaxf(fmaxf(bufB[c],bufB[c+1]),bufB[c+2]);
  }
  __syncthreads();
  // P4: B2[z18][y16][x16] = ymax(B1) -> bufB
  for (int idx=tid; idx<4608; idx+=256){
    int zz=idx>>8; int rem=idx&255; int yy=rem>>4; int xx=rem&15;
    int c = zz*288+yy*16+xx;
    bufB[idx] = fmaxf(fmaxf(bufA[c],bufA[c+16]),bufA[c+32]);
  }
  __syncthreads();
  // P5: open = zmax(B2); skel update
  #pragma unroll
  for(int j=0;j<16;j++){
    int c = j*256 + yy0*16 + xx0;
    float open_ = fmaxf(fmaxf(bufB[c],bufB[c+256]),bufB[c+512]);
    float d = fmaxf(ek[j]-open_, 0.f);
    int n = ((Z0+j)<<14)+((Y0+yy0)<<7)+(X0+xx0);
    if (INIT) skl[n] = d;
    else {
      float so = skl[n];
      skl[n] = so + fmaxf(d - so*d, 0.f);
    }
  }
}

// ---------------- whole binary soft-skel in ONE dispatch ----------------
__device__ __forceinline__ u64 berode_x(const u64* P, int tid){
  u64 c = P[tid];
  if (tid & 1) return c & ((c<<1)|(P[tid-1]>>63)) & ((c>>1)|(1ull<<63));
  else         return c & ((c<<1)|1ull) & ((c>>1)|(P[tid+1]<<63));
}
__device__ __forceinline__ u64 bdilate_x(const u64* P, int tid){
  u64 c = P[tid];
  if (tid & 1) return c | (c<<1) | (P[tid-1]>>63) | (c>>1);
  else         return c | (c<<1) | (c>>1) | (P[tid+1]<<63);
}

// grid: 2 masks x 2 batches x 16 z-chunks of 4 = 64 blocks; 11 iterations in-LDS
#define MAXP 28
__global__ __launch_bounds__(256) void bskel_all(const u64* __restrict__ bimg, u64* __restrict__ skel2)
{
  __shared__ u64 ping[MAXP][256];
  __shared__ u64 pong[MAXP][256];
  int bid = blockIdx.x;
  int zc = bid&15, b=(bid>>4)&1, m=bid>>5;
  int z0 = zc*4;
  int zl = max(0, z0-12), zh = min(64, z0+16);
  int cnt = zh - zl;
  size_t base = (size_t)m*NWORDS + (size_t)b*16384;
  const u64* vin = bimg + base;
  u64* skl = skel2 + base;
  int tid = threadIdx.x;
  int y = tid>>1;
  for(int p=0;p<cnt;p++) ping[p][tid] = vin[((zl+p)<<8)+tid];
  __syncthreads();
  u64 sk0=0, sk1=0, sk2=0, sk3=0;
  u64 (*A)[256] = ping; u64 (*B)[256] = pong;
  for(int k=0;k<11;k++){
    // E_{k+1} = erode(E_k): A -> B  (garbage outside valid range, never consumed)
    for(int p=0;p<cnt;p++){
      const u64* P = A[p];
      u64 r = berode_x(P, tid);
      if(y>0)   r &= P[tid-2];
      if(y<127) r &= P[tid+2];
      int gz = zl+p;
      if(gz>0)  r &= A[p>0?p-1:0][tid];
      if(gz<63) r &= A[p<cnt-1?p+1:cnt-1][tid];
      B[p][tid] = r;
    }
    __syncthreads();
    // skel |= E_k & ~dilate27(E_{k+1}) on the 4 output planes
    #pragma unroll
    for(int j=0;j<4;j++){
      int z = z0+j; int pz = z-zl;
      u64 D = 0;
      #pragma unroll
      for(int dz=-1;dz<=1;dz++){
        int zzg = z+dz; if(zzg<0 || zzg>=64) continue;
        const u64* P = B[pz+dz];
        u64 t = bdilate_x(P, tid);
        if(y>0)   t |= bdilate_x(P, tid-2);
        if(y<127) t |= bdilate_x(P, tid+2);
        D |= t;
      }
      u64 d = A[pz][tid] & ~D;
      if(j==0) sk0|=d; else if(j==1) sk1|=d; else if(j==2) sk2|=d; else sk3|=d;
    }
    __syncthreads();
    u64 (*T)[256]=A; A=B; B=T;
  }
  skl[((z0+0)<<8)+tid]=sk0;
  skl[((z0+1)<<8)+tid]=sk1;
  skl[((z0+2)<<8)+tid]=sk2;
  skl[((z0+3)<<8)+tid]=sk3;
}

// ---------------- separable Chebyshev EDT ----------------
__global__ __launch_bounds__(256) void edt_px(const u64* __restrict__ yb, const u64* __restrict__ hb,
                                              u8* __restrict__ d)
{
  int g = blockIdx.x*256 + threadIdx.x;
  int m = g >> 21;
  int n = g & (NTOT-1);
  const u64* bits = m ? hb : yb;
  int x = n & 127;
  int row = n >> 7;
  u64 w0 = bits[row*2], w1 = bits[row*2+1];
  int a = x - 31;
  u64 win;
  if (a < 0)        win = w0 << (-a);
  else if (a == 0)  win = w0;
  else if (a < 64)  win = (w0 >> a) | (w1 << (64-a));
  else              win = w1 >> (a-64);
  if (x < 31)  win |= (1ull << (31-x)) - 1;
  if (x > 95)  win |= (~0ull) << (159-x);
  u64 inv = ~win;
  u64 tl = inv & 0xFFFFFFFFull;
  u64 tr = inv >> 31;
  int dl = tl ? (31 - (63 - __clzll(tl))) : 99;
  int dr = tr ? (__ffsll((unsigned long long)tr) - 1) : 99;
  int dd = min(min(dl, dr), 16);
  d[(size_t)m*NTOT + n] = (u8)dd;
}

__global__ __launch_bounds__(256) void edt_py(const u8* __restrict__ din, u8* __restrict__ dout){
  int g = blockIdx.x*256 + threadIdx.x;
  int n = g & (NTOT-1);
  int c = (n >> 7) & 127;
  size_t idx = (size_t)(g>>21)*NTOT + n;
  int best = din[idx];
  #pragma unroll 4
  for (int k=1; k<=16; ++k){
    if (best <= k) break;
    int v = 255;
    if (c-k >= 0)   v = din[idx - (size_t)k*128];
    if (c+k < 128)  v = min(v, (int)din[idx + (size_t)k*128]);
    best = min(best, max(k, v));
  }
  dout[idx] = (u8)best;
}

// z-pass + per-block skeleton-radius max/min partials
__global__ __launch_bounds__(256) void edt_pz_part(const u8* __restrict__ din, u8* __restrict__ dout,
    const u64* __restrict__ skel2, const u64* __restrict__ hbits,
    u8* __restrict__ pmax, u8* __restrict__ pmin)
{
  int tid = threadIdx.x;
  int g = blockIdx.x*256 + tid;
  int m = g >> 21;
  int n = g & (NTOT-1);
  int c = (n >> 14) & 63;
  size_t idx = (size_t)m*NTOT + n;
  int best = din[idx];
  #pragma unroll 4
  for (int k=1; k<=16; ++k){
    if (best <= k) break;
    int v = 255;
    if (c-k >= 0)  v = din[idx - (size_t)k*16384];
    if (c+k < 64)  v = min(v, (int)din[idx + (size_t)k*16384]);
    best = min(best, max(k, v));
  }
  dout[idx] = (u8)best;
  int wi = n>>6, bit = n&63;
  u64 sbit = m ? (skel2[NWORDS+wi] & hbits[wi]) : skel2[wi];
  u32 r = (u32)((sbit>>bit)&1ull) ? (u32)best : 0u;
  __shared__ u32 sx[256], sn_[256];
  sx[tid]=r; sn_[tid]=r;
  __syncthreads();
  for(int s=128;s>0;s>>=1){
    if(tid<s){
      if(sx[tid+s]>sx[tid]) sx[tid]=sx[tid+s];
      if(sn_[tid+s]<sn_[tid]) sn_[tid]=sn_[tid+s];
    }
    __syncthreads();
  }
  if(tid==0){ pmax[blockIdx.x]=(u8)sx[0]; pmin[blockIdx.x]=(u8)sn_[0]; }
}

// reduce 16384 block partials -> mm[8]
__global__ __launch_bounds__(256) void rmm2(const u8* __restrict__ pmax, const u8* __restrict__ pmin,
                                            u32* __restrict__ mm){
  __shared__ u8 smx[4][256], smn[4][256];
  int tid = threadIdx.x;
  u8 mx[4]={0,0,0,0}, mn[4]={255,255,255,255};
  for(int i=tid;i<16384;i+=256){
    int sel=i>>13, b=(i>>12)&1, cc=sel*2+b;
    u8 a=pmax[i], d=pmin[i];
    if(a>mx[cc]) mx[cc]=a;
    if(d<mn[cc]) mn[cc]=d;
  }
  #pragma unroll
  for(int cc=0;cc<4;cc++){ smx[cc][tid]=mx[cc]; smn[cc][tid]=mn[cc]; }
  __syncthreads();
  for(int s=128;s>0;s>>=1){
    if(tid<s){
      #pragma unroll
      for(int cc=0;cc<4;cc++){
        if(smx[cc][tid+s]>smx[cc][tid]) smx[cc][tid]=smx[cc][tid+s];
        if(smn[cc][tid+s]<smn[cc][tid]) smn[cc][tid]=smn[cc][tid+s];
      }
    }
    __syncthreads();
  }
  if(tid==0){
    #pragma unroll
    for(int cc=0;cc<4;cc++){
      int sel=cc>>1, b=cc&1;
      mm[sel*4+b]   = (u32)smx[cc][0];
      mm[sel*4+2+b] = (u32)smn[cc][0];
    }
  }
}

// ---------------- fused sobel + final reduce, 4 voxels per thread ----------------
__global__ __launch_bounds__(256) void k_tail(const float* __restrict__ net, const float* __restrict__ skelp,
    const u64* __restrict__ ybits, const u64* __restrict__ hbits, const u64* __restrict__ skel2,
    const u8* __restrict__ acc, const u8* __restrict__ y8, const u32* __restrict__ mm,
    double* __restrict__ part1)
{
  float rmaxT_[2], rminT_[2], rmaxH_[2], rminH_[2];
  for(int b=0;b<2;b++){
    rmaxT_[b]=fmaxf((float)mm[b],1.f);   rminT_[b]=fmaxf((float)mm[2+b],1.f);
    rmaxH_[b]=fmaxf((float)mm[4+b],1.f); rminH_[b]=fmaxf((float)mm[6+b],1.f);
  }
  const int SMi[3]={1,2,1}, DVi[3]={-1,0,1};
  int r = blockIdx.x*256 + threadIdx.x;   // exactly NTOT/4 threads
  int n0 = r<<2;
  int b = n0>>20, v0 = n0&(VOL-1);
  int xb = n0&127, y=(n0>>7)&127, z=(n0>>14)&63;
  const float* P = net + (size_t)b*(2*VOL);
  const u8* Y8 = y8 + ((size_t)b<<20);
  float gpx[4]={0,0,0,0}, gpy[4]={0,0,0,0}, gpz[4]={0,0,0,0};
  int   gtx[4]={0,0,0,0}, gty[4]={0,0,0,0}, gtz[4]={0,0,0,0};
  #pragma unroll
  for(int da=0;da<3;da++){
    int zz=z+da-1; if((unsigned)zz>=64u) continue;
    #pragma unroll
    for(int db=0;db<3;db++){
      int yy=y+db-1; if((unsigned)yy>=128u) continue;
      int rb_ = (zz<<14)+(yy<<7)+xb;
      float pv[6]; int tv[6];
      #pragma unroll
      for(int j=0;j<6;j++){
        int xx = xb-1+j;
        bool ok = (unsigned)xx<128u;
        pv[j] = ok ? P[rb_-1+j] : 0.f;
        tv[j] = ok ? (int)Y8[rb_-1+j] : 0;
      }
      int smb=SMi[db], sma=SMi[da], dva=DVi[da];
      #pragma unroll
      for(int e=0;e<4;e++){
        float ep = pv[e+2]-pv[e], sp = pv[e]+2.f*pv[e+1]+pv[e+2];
        gpx[e] += (float)smb*ep; gpy[e] += (float)sma*ep; gpz[e] += (float)dva*sp;
        int et = tv[e+2]-tv[e], st = tv[e]+2*tv[e+1]+tv[e+2];
        gtx[e] += smb*et; gty[e] += sma*et; gtz[e] += dva*st;
      }
    }
  }
  float4 X0 = *(const float4*)&P[v0];
  float4 X1 = *(const float4*)&P[VOL+v0];
  float4 SK = *(const float4*)&skelp[n0];
  uchar4 DT = *(const uchar4*)&acc[n0];
  uchar4 DH = *(const uchar4*)&acc[NTOT+n0];
  int wi0 = n0>>6, bit0 = n0&63;
  int ybq = (int)((ybits[wi0]>>bit0)&0xFull);
  int hdq = (int)((hbits[wi0]>>bit0)&0xFull);
  int sTq = (int)((skel2[wi0]>>bit0)&0xFull);
  int sHq = (int)((skel2[NWORDS+wi0]>>bit0)&0xFull);
  float fsob=0,fcl1=0,fcl2=0,fcl3=0,fcl4=0,fi1=0,fun1=0,fi2=0,fun2=0;
  #pragma unroll
  for(int e=0;e<4;e++){
    float ftx=(float)gtx[e], fty=(float)gty[e], ftz=(float)gtz[e];
    float np_=sqrtf(gpx[e]*gpx[e]+gpy[e]*gpy[e]+gpz[e]*gpz[e]);
    float nt_=sqrtf(ftx*ftx+fty*fty+ftz*ftz);
    float ip=1.f/fmaxf(np_,1e-12f), it=1.f/fmaxf(nt_,1e-12f);
    float num=(gpx[e]*ftx+gpy[e]*fty+gpz[e]*ftz)*ip*it;
    float den=fmaxf((np_*ip)*(nt_*it),1e-8f);
    fsob += num/den;
    int yb=(ybq>>e)&1, hd=(hdq>>e)&1, sT=(sTq>>e)&1, sH=(sHq>>e)&1;
    float dT=(float)((const u8*)&DT)[e], dH=(float)((const u8*)&DH)[e];
    float x0v=((const float*)&X0)[e], x1v=((const float*)&X1)[e];
    float p = 1.f/(1.f+__expf(x0v-x1v));
    float sk=((const float*)&SK)[e];
    fcl1 += sk*(float)yb;
    fcl2 += sk;
    float q_vl = yb ? fminf(dT,rmaxT_[b])/rmaxT_[b] : 0.f;
    if (sT){
      fcl3 += p; fcl4 += 1.f;
      float t=(rmaxT_[b]-dT+rminT_[b])/rmaxT_[b]; float q_sl=t*t;
      float q_vp = fminf(dH,rmaxH_[b])/rmaxH_[b]*p;
      fi2  += q_sl*__powf(q_vp+1e-4f,0.7f)*q_sl;
      fun2 += q_sl*(0.1f*q_vp+0.9f*q_sl);
    }
    if (sH & hd){
      float t=(rmaxH_[b]-dH+rminH_[b])/rmaxH_[b]; float q_sp=t*t*p;
      fi1  += q_sp*__powf(q_sp+1e-4f,0.7f)*q_vl;
      fun1 += q_sp*(0.1f*q_sp+0.9f*q_vl);
    }
  }
  __shared__ double sw[9][4];
  int wid = threadIdx.x>>6, lane = threadIdx.x&63;
  double vals[9] = {fsob,fcl1,fcl2,fcl3,fcl4,fi1,fun1,fi2,fun2};
  #pragma unroll
  for(int s=0;s<9;s++){ double rr = wred(vals[s]); if(lane==0) sw[s][wid]=rr; }
  __syncthreads();
  if(threadIdx.x==0){
    #pragma unroll
    for(int s=0;s<9;s++) part1[(size_t)s*PC1 + blockIdx.x] = sw[s][0]+sw[s][1]+sw[s][2]+sw[s][3];
  }
}

// ---------------- finalize scalar ----------------
__global__ __launch_bounds__(256) void k_finalize(const double* __restrict__ part0,
                                                  const double* __restrict__ part1,
                                                  float* __restrict__ out){
  __shared__ double sd[256];
  __shared__ double tot[14];
  for(int s=0;s<5;s++){
    double v=0;
    for(int i=threadIdx.x;i<PC0;i+=256) v += part0[(size_t)s*PC0+i];
    sd[threadIdx.x]=v; __syncthreads();
    for(int k=128;k>0;k>>=1){ if((int)threadIdx.x<k) sd[threadIdx.x]+=sd[threadIdx.x+k]; __syncthreads(); }
    if(threadIdx.x==0) tot[s]=sd[0];
    __syncthreads();
  }
  for(int s=0;s<9;s++){
    double v=0;
    for(int i=threadIdx.x;i<PC1;i+=256) v += part1[(size_t)s*PC1+i];
    sd[threadIdx.x]=v; __syncthreads();
    for(int k=128;k>0;k>>=1){ if((int)threadIdx.x<k) sd[threadIdx.x]+=sd[threadIdx.x+k]; __syncthreads(); }
    if(threadIdx.x==0) tot[5+s]=sd[0];
    __syncthreads();
  }
  if(threadIdx.x==0){
    const double N = (double)NTOT;
    double ce = tot[0]/N;
    double tp=tot[1], fp=tot[2]-tot[1], fn=tot[3]-tot[1];
    double dice = -((2.0*tp+1e-5)/(2.0*tp+fp+fn+1e-5));
    double conn = tot[4]/(2.0*N);
    double dir  = 1.0 - tot[5]/N;
    double tprec = (tot[6]+1.0)/(tot[7]+1.0);
    double tsens = (tot[8]+1.0)/(tot[9]+1.0);
    double cld = 1.0 - 2.0*tprec*tsens/(tprec+tsens);
    double u1 = 1.0 - (tot[10]+1.0)/(tot[11]+1.0);
    double u2 = 1.0 - (tot[12]+1.0)/(tot[13]+1.0);
    out[0] = (float)(dice+ce+cld+dir+conn+u1+u2);
  }
}

extern "C" void kernel_launch(void* const* d_in, const int* in_sizes, int n_in,
                              void* d_out, int out_size, void* d_ws, size_t ws_size,
                              hipStream_t stream)
{
  (void)in_sizes; (void)n_in; (void)out_size; (void)ws_size;
  const float* net = (const float*)d_in[0];
  const int*   tgt = (const int*)d_in[1];
  float* out = (float*)d_out;
  char* w = (char*)d_ws;
  const size_t MB = 1024*1024;
  float* F1 = (float*)(w + 0*MB);          // prob img (ping)
  float* F2 = (float*)(w + 8*MB);          // skel_pred (soft)
  float* F3 = (float*)(w + 16*MB);         // img pong
  u64* ybits = (u64*)(w + 24*MB);
  u64* hbits = ybits + NWORDS;
  u64* skel2 = hbits + NWORDS;             // [T][H]
  u64* bping = skel2 + 2*NWORDS;           // [T][H]
  u8*  dA    = (u8*)(bping + 2*NWORDS);    // 4 MB
  u8*  dB    = dA + (size_t)2*NTOT;        // 4 MB
  u8*  y8    = dB + (size_t)2*NTOT;        // 2 MB
  double* part0 = (double*)(y8 + (size_t)NTOT);
  double* part1 = part0 + (size_t)5*PC0;
  u8* pmax = (u8*)(part1 + (size_t)9*PC1);
  u8* pmin = pmax + 16384;
  u32* mm  = (u32*)(pmin + 16384);

  k_init<<<PC0, 256, 0, stream>>>(net, tgt, F1, ybits, hbits, bping, y8, part0);

  // whole binary skeleton (both masks, both batches): 1 dispatch
  bskel_all<<<64, 256, 0, stream>>>(bping, skel2);

  // float soft_skel(prob, 10): 11 tile dispatches (E-chain: 1 erode each)
  fskel<true><<<512,256,0,stream>>>(F1, F3, F2);
  {
    float* pi=F3; float* po=F1;
    for(int i=0;i<10;i++){ fskel<false><<<512,256,0,stream>>>(pi,po,F2); float* t=pi; pi=po; po=t; }
  }

  // separable Chebyshev EDT (+ fused skeleton-radius partials in z-pass)
  const int GE = (2*NTOT)/256;
  edt_px<<<GE,256,0,stream>>>(ybits, hbits, dA);
  edt_py<<<GE,256,0,stream>>>(dA, dB);
  edt_pz_part<<<GE,256,0,stream>>>(dB, dA, skel2, hbits, pmax, pmin);
  rmm2<<<1,256,0,stream>>>(pmax, pmin, mm);

  k_tail<<<PC1,256,0,stream>>>(net, F2, ybits, hbits, skel2, dA, y8, mm, part1);
  k_finalize<<<1,256,0,stream>>>(part0, part1, out);
}

// Round 6
// 533.220 us; speedup vs baseline: 1.5351x; 1.1645x over previous
//
#include <hip/hip_runtime.h>
#include <math.h>

typedef unsigned long long u64;
typedef unsigned int u32;
typedef unsigned char u8;

#define VOL 1048576              // 64*128*128
#define NTOT 2097152             // 2 batches
#define NWORDS 32768             // NTOT/64
#define PC0 8192                 // k_init blocks / partial stride
#define PC1 2048                 // k_tail blocks / partial stride
#define PINF 1e30f
#define NINF -1e30f

// ---------------- wave reduction helper ----------------
__device__ __forceinline__ double wred(double v){
  #pragma unroll
  for(int o=32;o;o>>=1) v += __shfl_down(v, o);
  return v;
}

// ---------------- init: prob, bitmasks, y8, dice/ce/conn sums ----------------
__global__ __launch_bounds__(256) void k_init(const float* __restrict__ net, const int* __restrict__ tgt,
    float* __restrict__ img, u64* __restrict__ ybits, u64* __restrict__ hbits,
    u64* __restrict__ bimg2, u8* __restrict__ y8, double* __restrict__ part)
{
  int n = blockIdx.x*256 + threadIdx.x;   // exactly NTOT threads
  int b = n >> 20;
  int v = n & (VOL-1);
  const float* nb = net + (size_t)b*(2*VOL);
  float x0 = nb[v], x1 = nb[VOL+v];
  int t = tgt[n];
  int yb = (t>0) ? 1 : 0;
  float p = 1.f/(1.f+__expf(x0-x1));
  img[n] = p;
  y8[n] = (u8)yb;
  u64 wy = __ballot(yb);
  u64 wh = __ballot(x1 > x0);
  if((threadIdx.x & 63)==0){
    int wi = n>>6;
    ybits[wi]=wy; hbits[wi]=wh;
    bimg2[wi]=wy; bimg2[NWORDS+wi]=wh;
  }
  float mx = fmaxf(x0,x1);
  float lse = mx + __logf(__expf(x0-mx)+__expf(x1-mx));
  double ce = (double)(lse - (yb ? x1 : x0));
  double tp = (double)p * yb;
  double spr = (double)p;
  double sy = (double)yb;
  double conn = (double)((int)((x0>0.5f)!=(yb!=0)) + (int)((x1>0.5f)!=(yb!=0)));
  __shared__ double sw[5][4];
  int wid = threadIdx.x>>6, lane = threadIdx.x&63;
  double vals[5] = {ce,tp,spr,sy,conn};
  #pragma unroll
  for(int s=0;s<5;s++){ double r = wred(vals[s]); if(lane==0) sw[s][wid]=r; }
  __syncthreads();
  if(threadIdx.x==0){
    #pragma unroll
    for(int s=0;s<5;s++) part[(size_t)s*PC0 + blockIdx.x] = sw[s][0]+sw[s][1]+sw[s][2]+sw[s][3];
  }
}

// ---------------- tile-fused float soft-skel step (E-chain), 32x8x8 tile ----------------
// Load E_k (36x12x12 halo2), E_{k+1}=erode (34x10x10), write center, separable dilate27,
// skel update. 34 KB LDS -> 4 blocks/CU, 1024 blocks.
#define LDX 36
#define LDY 12
#define LDZ 12
#define LDN (LDX*LDY*LDZ)        // 5184
#define LZS (LDX*LDY)            // 432
#define E1X 34
#define E1Y 10
#define E1Z 10
#define E1N (E1X*E1Y*E1Z)        // 3400
#define E1S (E1X*E1Y)            // 340

template<bool INIT>
__global__ __launch_bounds__(256) void fskel(const float* __restrict__ imgin, float* __restrict__ imgout,
                                             float* __restrict__ skel)
{
  __shared__ float bufA[LDN];    // E_k load; reused as B1 [z10][y10][x32]=3200
  __shared__ float bufB[E1N];    // E_{k+1}; reused as B2 [z10][y8][x32]=2560
  int bid = blockIdx.x;
  int xb = bid&3, yb=(bid>>2)&15, zb=(bid>>6)&7, b=bid>>9;
  int X0=xb*32, Y0=yb*8, Z0=zb*8;
  const float* vol = imgin + (size_t)b*VOL;
  float* volo = imgout + (size_t)b*VOL;
  float* skl = skel + (size_t)b*VOL;
  int tid = threadIdx.x;
  // P0: load E_k halo2 (OOB -> +INF, erode-neutral)
  for (int idx=tid; idx<LDN; idx+=256){
    int zz = idx/LZS; int rem = idx-zz*LZS; int yy=rem/LDX; int xx=rem-yy*LDX;
    int gz=Z0-2+zz, gy=Y0-2+yy, gx=X0-2+xx;
    float v=PINF;
    if((unsigned)gz<64u && (unsigned)gy<128u && (unsigned)gx<128u)
      v = vol[(gz<<14)+(gy<<7)+gx];
    bufA[idx]=v;
  }
  __syncthreads();
  // P1: E_{k+1} = erode7(E_k) on halo1 region (OOB position -> -INF)
  for (int idx=tid; idx<E1N; idx+=256){
    int zz=idx/E1S; int rem=idx-zz*E1S; int yy=rem/E1X; int xx=rem-yy*E1X;
    int gz=Z0-1+zz, gy=Y0-1+yy, gx=X0-1+xx;
    float v=NINF;
    if((unsigned)gz<64u && (unsigned)gy<128u && (unsigned)gx<128u){
      int c=(zz+1)*LZS+(yy+1)*LDX+(xx+1);
      v = fminf(fminf(bufA[c-1],bufA[c]),bufA[c+1]);
      v = fminf(v, fminf(bufA[c-LDX],bufA[c+LDX]));
      v = fminf(v, fminf(bufA[c-LZS],bufA[c+LZS]));
    }
    bufB[idx]=v;
  }
  __syncthreads();
  // P2: snapshot E_k center to regs; write E_{k+1} center to global
  int yy0 = tid>>5, xx0 = tid&31;     // 8y x 32x
  float ek[8];
  #pragma unroll
  for(int j=0;j<8;j++){
    ek[j] = bufA[(j+2)*LZS+(yy0+2)*LDX+(xx0+2)];
    int n = ((Z0+j)<<14)+((Y0+yy0)<<7)+(X0+xx0);
    volo[n] = bufB[(j+1)*E1S+(yy0+1)*E1X+(xx0+1)];
  }
  __syncthreads();
  // P3: B1[z10][y10][x32] = xmax(E_{k+1}) -> bufA
  for (int idx=tid; idx<3200; idx+=256){
    int zz=idx/320; int rem=idx-zz*320; int yy=rem>>5; int xx=rem&31;
    int c = zz*E1S+yy*E1X+xx;
    bufA[idx] = fmaxf(fmaxf(bufB[c],bufB[c+1]),bufB[c+2]);
  }
  __syncthreads();
  // P4: B2[z10][y8][x32] = ymax(B1) -> bufB
  for (int idx=tid; idx<2560; idx+=256){
    int zz=idx>>8; int rem=idx&255; int yy=rem>>5; int xx=rem&31;
    int c = zz*320+yy*32+xx;
    bufB[idx] = fmaxf(fmaxf(bufA[c],bufA[c+32]),bufA[c+64]);
  }
  __syncthreads();
  // P5: open = zmax(B2); skel update
  #pragma unroll
  for(int j=0;j<8;j++){
    int c = j*256 + yy0*32 + xx0;
    float open_ = fmaxf(fmaxf(bufB[c],bufB[c+256]),bufB[c+512]);
    float d = fmaxf(ek[j]-open_, 0.f);
    int n = ((Z0+j)<<14)+((Y0+yy0)<<7)+(X0+xx0);
    if (INIT) skl[n] = d;
    else {
      float so = skl[n];
      skl[n] = so + fmaxf(d - so*d, 0.f);
    }
  }
}

// ---------------- systolic fused binary soft-skel iteration (bit-planes) ----------------
__device__ __forceinline__ u64 berode_x(const u64* P, int tid){
  u64 c = P[tid];
  if (tid & 1) return c & ((c<<1)|(P[tid-1]>>63)) & ((c>>1)|(1ull<<63));
  else         return c & ((c<<1)|1ull) & ((c>>1)|(P[tid+1]<<63));
}
__device__ __forceinline__ u64 bdilate_x(const u64* P, int tid){
  u64 c = P[tid];
  if (tid & 1) return c | (c<<1) | (P[tid-1]>>63) | (c>>1);
  else         return c | (c<<1) | (c>>1) | (P[tid+1]<<63);
}

// 64 blocks: 2 masks x 2 batches x 16 z-chunks of 4; 14 systolic steps, 1 barrier each
template<bool INIT>
__global__ __launch_bounds__(256) void bskel(const u64* __restrict__ imgin, u64* __restrict__ imgout,
                                             u64* __restrict__ skel)
{
  __shared__ u64 simg[4][256];
  __shared__ u64 se1[6][256];
  __shared__ u64 se2[2][256];
  __shared__ u64 sM[4][256];
  int bid = blockIdx.x;
  int tzb = bid & 15, b = (bid>>4)&1, m = bid>>5;
  int z0 = tzb*4, z1 = z0+4;
  size_t base = (size_t)m*NWORDS + (size_t)b*16384;
  const u64* vin = imgin + base;
  u64* vout = imgout + base;
  u64* skl = skel + base;
  int tid = threadIdx.x;
  int y = tid>>1;

  for (int s = z0-3; s <= z1+6; ++s){
    if (s <= z1+2)
      simg[(s+96)&3][tid] = ((unsigned)s<64u) ? vin[(s<<8)+tid] : ~0ull;
    { int t = s-2;
      if (t >= z0-2 && t <= z1+1){
        u64 r = ~0ull;
        if ((unsigned)t<64u){
          const u64* P = simg[(t+96)&3];
          if (INIT) r = P[tid];
          else {
            r = berode_x(P, tid);
            if(y>0)   r &= P[tid-2];
            if(y<127) r &= P[tid+2];
            r &= simg[(t-1+96)&3][tid] & simg[(t+1+96)&3][tid];
          }
        }
        se1[(t+96)%6][tid] = r;
      }
    }
    { int t = s-4;
      if (t >= z0-1 && t <= z1){
        u64 r = 0;
        if ((unsigned)t<64u){
          const u64* P = se1[(t+96)%6];
          r = berode_x(P, tid);
          if(y>0)   r &= P[tid-2];
          if(y<127) r &= P[tid+2];
          r &= se1[(t-1+96)%6][tid] & se1[(t+1+96)%6][tid];
        }
        se2[(t+96)&1][tid] = r;
      }
    }
    { int t = s-5;
      if (t >= z0-1 && t <= z1){
        const u64* P = se2[(t+96)&1];
        u64 dm = bdilate_x(P, tid);
        if(y>0)   dm |= bdilate_x(P, tid-2);
        if(y<127) dm |= bdilate_x(P, tid+2);
        sM[(t+96)&3][tid] = dm;
      }
    }
    { int z = s-7;
      if (z >= z0 && z < z1){
        u64 open_ = sM[(z-1+96)&3][tid] | sM[(z+96)&3][tid] | sM[(z+1+96)&3][tid];
        u64 e1v = se1[(z+96)%6][tid];
        u64 d = e1v & ~open_;
        int gw = (z<<8)+tid;
        if (INIT) skl[gw] = d;
        else { skl[gw] |= d; vout[gw] = e1v; }
      }
    }
    __syncthreads();
  }
}

// ---------------- separable Chebyshev EDT ----------------
__global__ __launch_bounds__(256) void edt_px(const u64* __restrict__ yb, const u64* __restrict__ hb,
                                              u8* __restrict__ d)
{
  int g = blockIdx.x*256 + threadIdx.x;
  int m = g >> 21;
  int n = g & (NTOT-1);
  const u64* bits = m ? hb : yb;
  int x = n & 127;
  int row = n >> 7;
  u64 w0 = bits[row*2], w1 = bits[row*2+1];
  int a = x - 31;
  u64 win;
  if (a < 0)        win = w0 << (-a);
  else if (a == 0)  win = w0;
  else if (a < 64)  win = (w0 >> a) | (w1 << (64-a));
  else              win = w1 >> (a-64);
  if (x < 31)  win |= (1ull << (31-x)) - 1;
  if (x > 95)  win |= (~0ull) << (159-x);
  u64 inv = ~win;
  u64 tl = inv & 0xFFFFFFFFull;
  u64 tr = inv >> 31;
  int dl = tl ? (31 - (63 - __clzll(tl))) : 99;
  int dr = tr ? (__ffsll((unsigned long long)tr) - 1) : 99;
  int dd = min(min(dl, dr), 16);
  d[(size_t)m*NTOT + n] = (u8)dd;
}

__global__ __launch_bounds__(256) void edt_py(const u8* __restrict__ din, u8* __restrict__ dout){
  int g = blockIdx.x*256 + threadIdx.x;
  int n = g & (NTOT-1);
  int c = (n >> 7) & 127;
  size_t idx = (size_t)(g>>21)*NTOT + n;
  int best = din[idx];
  #pragma unroll 4
  for (int k=1; k<=16; ++k){
    if (best <= k) break;
    int v = 255;
    if (c-k >= 0)   v = din[idx - (size_t)k*128];
    if (c+k < 128)  v = min(v, (int)din[idx + (size_t)k*128]);
    best = min(best, max(k, v));
  }
  dout[idx] = (u8)best;
}

// z-pass + per-block skeleton-radius max/min partials
__global__ __launch_bounds__(256) void edt_pz_part(const u8* __restrict__ din, u8* __restrict__ dout,
    const u64* __restrict__ skel2, const u64* __restrict__ hbits,
    u8* __restrict__ pmax, u8* __restrict__ pmin)
{
  int tid = threadIdx.x;
  int g = blockIdx.x*256 + tid;
  int m = g >> 21;
  int n = g & (NTOT-1);
  int c = (n >> 14) & 63;
  size_t idx = (size_t)m*NTOT + n;
  int best = din[idx];
  #pragma unroll 4
  for (int k=1; k<=16; ++k){
    if (best <= k) break;
    int v = 255;
    if (c-k >= 0)  v = din[idx - (size_t)k*16384];
    if (c+k < 64)  v = min(v, (int)din[idx + (size_t)k*16384]);
    best = min(best, max(k, v));
  }
  dout[idx] = (u8)best;
  int wi = n>>6, bit = n&63;
  u64 sbit = m ? (skel2[NWORDS+wi] & hbits[wi]) : skel2[wi];
  u32 r = (u32)((sbit>>bit)&1ull) ? (u32)best : 0u;
  __shared__ u32 sx[256], sn_[256];
  sx[tid]=r; sn_[tid]=r;
  __syncthreads();
  for(int s=128;s>0;s>>=1){
    if(tid<s){
      if(sx[tid+s]>sx[tid]) sx[tid]=sx[tid+s];
      if(sn_[tid+s]<sn_[tid]) sn_[tid]=sn_[tid+s];
    }
    __syncthreads();
  }
  if(tid==0){ pmax[blockIdx.x]=(u8)sx[0]; pmin[blockIdx.x]=(u8)sn_[0]; }
}

// reduce 16384 block partials -> mm[8]
__global__ __launch_bounds__(256) void rmm2(const u8* __restrict__ pmax, const u8* __restrict__ pmin,
                                            u32* __restrict__ mm){
  __shared__ u8 smx[4][256], smn[4][256];
  int tid = threadIdx.x;
  u8 mx[4]={0,0,0,0}, mn[4]={255,255,255,255};
  for(int i=tid;i<16384;i+=256){
    int sel=i>>13, b=(i>>12)&1, cc=sel*2+b;
    u8 a=pmax[i], d=pmin[i];
    if(a>mx[cc]) mx[cc]=a;
    if(d<mn[cc]) mn[cc]=d;
  }
  #pragma unroll
  for(int cc=0;cc<4;cc++){ smx[cc][tid]=mx[cc]; smn[cc][tid]=mn[cc]; }
  __syncthreads();
  for(int s=128;s>0;s>>=1){
    if(tid<s){
      #pragma unroll
      for(int cc=0;cc<4;cc++){
        if(smx[cc][tid+s]>smx[cc][tid]) smx[cc][tid]=smx[cc][tid+s];
        if(smn[cc][tid+s]<smn[cc][tid]) smn[cc][tid]=smn[cc][tid+s];
      }
    }
    __syncthreads();
  }
  if(tid==0){
    #pragma unroll
    for(int cc=0;cc<4;cc++){
      int sel=cc>>1, b=cc&1;
      mm[sel*4+b]   = (u32)smx[cc][0];
      mm[sel*4+2+b] = (u32)smn[cc][0];
    }
  }
}

// ---------------- fused sobel + final reduce, 4 voxels per thread ----------------
__global__ __launch_bounds__(256) void k_tail(const float* __restrict__ net, const float* __restrict__ skelp,
    const u64* __restrict__ ybits, const u64* __restrict__ hbits, const u64* __restrict__ skel2,
    const u8* __restrict__ acc, const u8* __restrict__ y8, const u32* __restrict__ mm,
    double* __restrict__ part1)
{
  float rmaxT_[2], rminT_[2], rmaxH_[2], rminH_[2];
  for(int b=0;b<2;b++){
    rmaxT_[b]=fmaxf((float)mm[b],1.f);   rminT_[b]=fmaxf((float)mm[2+b],1.f);
    rmaxH_[b]=fmaxf((float)mm[4+b],1.f); rminH_[b]=fmaxf((float)mm[6+b],1.f);
  }
  const int SMi[3]={1,2,1}, DVi[3]={-1,0,1};
  int r = blockIdx.x*256 + threadIdx.x;   // exactly NTOT/4 threads
  int n0 = r<<2;
  int b = n0>>20, v0 = n0&(VOL-1);
  int xb = n0&127, y=(n0>>7)&127, z=(n0>>14)&63;
  const float* P = net + (size_t)b*(2*VOL);
  const u8* Y8 = y8 + ((size_t)b<<20);
  float gpx[4]={0,0,0,0}, gpy[4]={0,0,0,0}, gpz[4]={0,0,0,0};
  int   gtx[4]={0,0,0,0}, gty[4]={0,0,0,0}, gtz[4]={0,0,0,0};
  #pragma unroll
  for(int da=0;da<3;da++){
    int zz=z+da-1; if((unsigned)zz>=64u) continue;
    #pragma unroll
    for(int db=0;db<3;db++){
      int yy=y+db-1; if((unsigned)yy>=128u) continue;
      int rb_ = (zz<<14)+(yy<<7)+xb;
      float pv[6]; int tv[6];
      #pragma unroll
      for(int j=0;j<6;j++){
        int xx = xb-1+j;
        bool ok = (unsigned)xx<128u;
        pv[j] = ok ? P[rb_-1+j] : 0.f;
        tv[j] = ok ? (int)Y8[rb_-1+j] : 0;
      }
      int smb=SMi[db], sma=SMi[da], dva=DVi[da];
      #pragma unroll
      for(int e=0;e<4;e++){
        float ep = pv[e+2]-pv[e], sp = pv[e]+2.f*pv[e+1]+pv[e+2];
        gpx[e] += (float)smb*ep; gpy[e] += (float)sma*ep; gpz[e] += (float)dva*sp;
        int et = tv[e+2]-tv[e], st = tv[e]+2*tv[e+1]+tv[e+2];
        gtx[e] += smb*et; gty[e] += sma*et; gtz[e] += dva*st;
      }
    }
  }
  float4 X0 = *(const float4*)&P[v0];
  float4 X1 = *(const float4*)&P[VOL+v0];
  float4 SK = *(const float4*)&skelp[n0];
  uchar4 DT = *(const uchar4*)&acc[n0];
  uchar4 DH = *(const uchar4*)&acc[NTOT+n0];
  int wi0 = n0>>6, bit0 = n0&63;
  int ybq = (int)((ybits[wi0]>>bit0)&0xFull);
  int hdq = (int)((hbits[wi0]>>bit0)&0xFull);
  int sTq = (int)((skel2[wi0]>>bit0)&0xFull);
  int sHq = (int)((skel2[NWORDS+wi0]>>bit0)&0xFull);
  float fsob=0,fcl1=0,fcl2=0,fcl3=0,fcl4=0,fi1=0,fun1=0,fi2=0,fun2=0;
  #pragma unroll
  for(int e=0;e<4;e++){
    float ftx=(float)gtx[e], fty=(float)gty[e], ftz=(float)gtz[e];
    float np_=sqrtf(gpx[e]*gpx[e]+gpy[e]*gpy[e]+gpz[e]*gpz[e]);
    float nt_=sqrtf(ftx*ftx+fty*fty+ftz*ftz);
    float ip=1.f/fmaxf(np_,1e-12f), it=1.f/fmaxf(nt_,1e-12f);
    float num=(gpx[e]*ftx+gpy[e]*fty+gpz[e]*ftz)*ip*it;
    float den=fmaxf((np_*ip)*(nt_*it),1e-8f);
    fsob += num/den;
    int yb=(ybq>>e)&1, hd=(hdq>>e)&1, sT=(sTq>>e)&1, sH=(sHq>>e)&1;
    float dT=(float)((const u8*)&DT)[e], dH=(float)((const u8*)&DH)[e];
    float x0v=((const float*)&X0)[e], x1v=((const float*)&X1)[e];
    float p = 1.f/(1.f+__expf(x0v-x1v));
    float sk=((const float*)&SK)[e];
    fcl1 += sk*(float)yb;
    fcl2 += sk;
    float q_vl = yb ? fminf(dT,rmaxT_[b])/rmaxT_[b] : 0.f;
    if (sT){
      fcl3 += p; fcl4 += 1.f;
      float t=(rmaxT_[b]-dT+rminT_[b])/rmaxT_[b]; float q_sl=t*t;
      float q_vp = fminf(dH,rmaxH_[b])/rmaxH_[b]*p;
      fi2  += q_sl*__powf(q_vp+1e-4f,0.7f)*q_sl;
      fun2 += q_sl*(0.1f*q_vp+0.9f*q_sl);
    }
    if (sH & hd){
      float t=(rmaxH_[b]-dH+rminH_[b])/rmaxH_[b]; float q_sp=t*t*p;
      fi1  += q_sp*__powf(q_sp+1e-4f,0.7f)*q_vl;
      fun1 += q_sp*(0.1f*q_sp+0.9f*q_vl);
    }
  }
  __shared__ double sw[9][4];
  int wid = threadIdx.x>>6, lane = threadIdx.x&63;
  double vals[9] = {fsob,fcl1,fcl2,fcl3,fcl4,fi1,fun1,fi2,fun2};
  #pragma unroll
  for(int s=0;s<9;s++){ double rr = wred(vals[s]); if(lane==0) sw[s][wid]=rr; }
  __syncthreads();
  if(threadIdx.x==0){
    #pragma unroll
    for(int s=0;s<9;s++) part1[(size_t)s*PC1 + blockIdx.x] = sw[s][0]+sw[s][1]+sw[s][2]+sw[s][3];
  }
}

// ---------------- finalize scalar ----------------
__global__ __launch_bounds__(256) void k_finalize(const double* __restrict__ part0,
                                                  const double* __restrict__ part1,
                                                  float* __restrict__ out){
  __shared__ double sd[256];
  __shared__ double tot[14];
  for(int s=0;s<5;s++){
    double v=0;
    for(int i=threadIdx.x;i<PC0;i+=256) v += part0[(size_t)s*PC0+i];
    sd[threadIdx.x]=v; __syncthreads();
    for(int k=128;k>0;k>>=1){ if((int)threadIdx.x<k) sd[threadIdx.x]+=sd[threadIdx.x+k]; __syncthreads(); }
    if(threadIdx.x==0) tot[s]=sd[0];
    __syncthreads();
  }
  for(int s=0;s<9;s++){
    double v=0;
    for(int i=threadIdx.x;i<PC1;i+=256) v += part1[(size_t)s*PC1+i];
    sd[threadIdx.x]=v; __syncthreads();
    for(int k=128;k>0;k>>=1){ if((int)threadIdx.x<k) sd[threadIdx.x]+=sd[threadIdx.x+k]; __syncthreads(); }
    if(threadIdx.x==0) tot[5+s]=sd[0];
    __syncthreads();
  }
  if(threadIdx.x==0){
    const double N = (double)NTOT;
    double ce = tot[0]/N;
    double tp=tot[1], fp=tot[2]-tot[1], fn=tot[3]-tot[1];
    double dice = -((2.0*tp+1e-5)/(2.0*tp+fp+fn+1e-5));
    double conn = tot[4]/(2.0*N);
    double dir  = 1.0 - tot[5]/N;
    double tprec = (tot[6]+1.0)/(tot[7]+1.0);
    double tsens = (tot[8]+1.0)/(tot[9]+1.0);
    double cld = 1.0 - 2.0*tprec*tsens/(tprec+tsens);
    double u1 = 1.0 - (tot[10]+1.0)/(tot[11]+1.0);
    double u2 = 1.0 - (tot[12]+1.0)/(tot[13]+1.0);
    out[0] = (float)(dice+ce+cld+dir+conn+u1+u2);
  }
}

extern "C" void kernel_launch(void* const* d_in, const int* in_sizes, int n_in,
                              void* d_out, int out_size, void* d_ws, size_t ws_size,
                              hipStream_t stream)
{
  (void)in_sizes; (void)n_in; (void)out_size; (void)ws_size;
  const float* net = (const float*)d_in[0];
  const int*   tgt = (const int*)d_in[1];
  float* out = (float*)d_out;
  char* w = (char*)d_ws;
  const size_t MB = 1024*1024;
  float* F1 = (float*)(w + 0*MB);          // prob img (ping)
  float* F2 = (float*)(w + 8*MB);          // skel_pred (soft)
  float* F3 = (float*)(w + 16*MB);         // img pong
  u64* ybits = (u64*)(w + 24*MB);
  u64* hbits = ybits + NWORDS;
  u64* skel2 = hbits + NWORDS;             // [T][H]
  u64* bping = skel2 + 2*NWORDS;           // [T][H]
  u64* bpong = bping + 2*NWORDS;
  u8*  dA    = (u8*)(bpong + 2*NWORDS);    // 4 MB
  u8*  dB    = dA + (size_t)2*NTOT;        // 4 MB
  u8*  y8    = dB + (size_t)2*NTOT;        // 2 MB
  double* part0 = (double*)(y8 + (size_t)NTOT);
  double* part1 = part0 + (size_t)5*PC0;
  u8* pmax = (u8*)(part1 + (size_t)9*PC1);
  u8* pmin = pmax + 16384;
  u32* mm  = (u32*)(pmin + 16384);

  k_init<<<PC0, 256, 0, stream>>>(net, tgt, F1, ybits, hbits, bping, y8, part0);

  // binary soft_skel for y_true and hard: 11 systolic dispatches (64 blocks each)
  bskel<true><<<64,256,0,stream>>>(bping, bpong, skel2);
  {
    u64* pi=bping; u64* po=bpong;
    for(int i=0;i<10;i++){ bskel<false><<<64,256,0,stream>>>(pi,po,skel2); u64* t=pi; pi=po; po=t; }
  }

  // float soft_skel(prob, 10): 11 tile dispatches (E-chain: 1 erode each), 1024 blocks
  fskel<true><<<1024,256,0,stream>>>(F1, F3, F2);
  {
    float* pi=F3; float* po=F1;
    for(int i=0;i<10;i++){ fskel<false><<<1024,256,0,stream>>>(pi,po,F2); float* t=pi; pi=po; po=t; }
  }

  // separable Chebyshev EDT (+ fused skeleton-radius partials in z-pass)
  const int GE = (2*NTOT)/256;
  edt_px<<<GE,256,0,stream>>>(ybits, hbits, dA);
  edt_py<<<GE,256,0,stream>>>(dA, dB);
  edt_pz_part<<<GE,256,0,stream>>>(dB, dA, skel2, hbits, pmax, pmin);
  rmm2<<<1,256,0,stream>>>(pmax, pmin, mm);

  k_tail<<<PC1,256,0,stream>>>(net, F2, ybits, hbits, skel2, dA, y8, mm, part1);
  k_finalize<<<1,256,0,stream>>>(part0, part1, out);
}

// Round 7
// 443.735 us; speedup vs baseline: 1.8447x; 1.2017x over previous
//
#include <hip/hip_runtime.h>
#include <math.h>

typedef unsigned long long u64;
typedef unsigned int u32;
typedef unsigned short u16;
typedef unsigned char u8;

#define VOL 1048576              // 64*128*128
#define NTOT 2097152             // 2 batches
#define NWORDS 32768             // NTOT/64
#define PC0 8192                 // k_init blocks / partial stride
#define PC1 2048                 // k_tail blocks / partial stride

// fp16 <-> fp32 helpers via native _Float16 (no half-API dependence)
union HU { u16 u; _Float16 h; };
__device__ __forceinline__ float h2f(u16 u){ HU x; x.u=u; return (float)x.h; }
__device__ __forceinline__ u16 f2h(float f){ HU x; x.h=(_Float16)f; return x.u; }
#define H_ONE  0x3C00u   // 1.0 (erode-neutral: all values in [0,1])
#define H_ZERO 0x0000u   // 0.0 (dilate-neutral)

// ---------------- wave reduction helper ----------------
__device__ __forceinline__ double wred(double v){
  #pragma unroll
  for(int o=32;o;o>>=1) v += __shfl_down(v, o);
  return v;
}

// ---------------- init: prob(fp16), bitmasks, y8, dice/ce/conn sums ----------------
__global__ __launch_bounds__(256) void k_init(const float* __restrict__ net, const int* __restrict__ tgt,
    u16* __restrict__ img, u64* __restrict__ ybits, u64* __restrict__ hbits,
    u64* __restrict__ bimg2, u8* __restrict__ y8, double* __restrict__ part)
{
  int n = blockIdx.x*256 + threadIdx.x;   // exactly NTOT threads
  int b = n >> 20;
  int v = n & (VOL-1);
  const float* nb = net + (size_t)b*(2*VOL);
  float x0 = nb[v], x1 = nb[VOL+v];
  int t = tgt[n];
  int yb = (t>0) ? 1 : 0;
  float p = 1.f/(1.f+__expf(x0-x1));
  img[n] = f2h(p);
  y8[n] = (u8)yb;
  u64 wy = __ballot(yb);
  u64 wh = __ballot(x1 > x0);
  if((threadIdx.x & 63)==0){
    int wi = n>>6;
    ybits[wi]=wy; hbits[wi]=wh;
    bimg2[wi]=wy; bimg2[NWORDS+wi]=wh;
  }
  float mx = fmaxf(x0,x1);
  float lse = mx + __logf(__expf(x0-mx)+__expf(x1-mx));
  double ce = (double)(lse - (yb ? x1 : x0));
  double tp = (double)p * yb;
  double spr = (double)p;
  double sy = (double)yb;
  double conn = (double)((int)((x0>0.5f)!=(yb!=0)) + (int)((x1>0.5f)!=(yb!=0)));
  __shared__ double sw[5][4];
  int wid = threadIdx.x>>6, lane = threadIdx.x&63;
  double vals[5] = {ce,tp,spr,sy,conn};
  #pragma unroll
  for(int s=0;s<5;s++){ double r = wred(vals[s]); if(lane==0) sw[s][wid]=r; }
  __syncthreads();
  if(threadIdx.x==0){
    #pragma unroll
    for(int s=0;s<5;s++) part[(size_t)s*PC0 + blockIdx.x] = sw[s][0]+sw[s][1]+sw[s][2]+sw[s][3];
  }
}

// ---------------- fp16 tile-fused float soft-skel step (E-chain), 32x8x4 tile ----------------
// grid 2048 = 8 blocks/CU, ~11 KB LDS -> 32 waves/CU. Integer min/max on fp16 bits
// (exact: all values nonneg fp16, ordering == unsigned ordering).
#define TXF 32
#define TYF 8
#define TZF 4
#define LDX 36
#define LDY 12
#define LDZ 8
#define LZS (LDX*LDY)            // 432
#define LDN (LZS*LDZ)            // 3456
#define E1X 34
#define E1Y 10
#define E1Z 6
#define E1S (E1X*E1Y)            // 340
#define E1N (E1S*E1Z)            // 2040
#define B1N 1920                 // [6][10][32], z-stride 320
#define B2N 1536                 // [6][8][32],  z-stride 256

template<bool INIT>
__global__ __launch_bounds__(256) void fskel(const u16* __restrict__ imgin, u16* __restrict__ imgout,
                                             u16* __restrict__ skel, int wimg)
{
  __shared__ u16 bufA[LDN];      // E_k halo2; reused as B1
  __shared__ u16 bufB[E1N];      // E_{k+1} halo1; reused as B2
  int bid = blockIdx.x;
  int xb = bid&3, yb=(bid>>2)&15, zb=(bid>>6)&15, b=bid>>10;
  int X0=xb*TXF, Y0=yb*TYF, Z0=zb*TZF;
  const u16* vin = imgin + (size_t)b*VOL;
  u16* vout = imgout + (size_t)b*VOL;
  u16* skl = skel + (size_t)b*VOL;
  int tid = threadIdx.x;
  // P0: load E_k halo2 (OOB -> 1.0, erode-neutral)
  for (int idx=tid; idx<LDN; idx+=256){
    int zz = idx/LZS; int rem = idx-zz*LZS; int yy=rem/LDX; int xx=rem-yy*LDX;
    int gz=Z0-2+zz, gy=Y0-2+yy, gx=X0-2+xx;
    u16 v=H_ONE;
    if((unsigned)gz<64u && (unsigned)gy<128u && (unsigned)gx<128u)
      v = vin[(gz<<14)+(gy<<7)+gx];
    bufA[idx]=v;
  }
  __syncthreads();
  // P1: E_{k+1} = erode7(E_k) on halo1 (OOB position -> 0.0, dilate-neutral)
  for (int idx=tid; idx<E1N; idx+=256){
    int zz=idx/E1S; int rem=idx-zz*E1S; int yy=rem/E1X; int xx=rem-yy*E1X;
    int gz=Z0-1+zz, gy=Y0-1+yy, gx=X0-1+xx;
    u32 v=H_ZERO;
    if((unsigned)gz<64u && (unsigned)gy<128u && (unsigned)gx<128u){
      int c=(zz+1)*LZS+(yy+1)*LDX+(xx+1);
      u32 m = min((u32)bufA[c-1], (u32)bufA[c]);
      m = min(m, (u32)bufA[c+1]);
      m = min(m, min((u32)bufA[c-LDX],(u32)bufA[c+LDX]));
      m = min(m, min((u32)bufA[c-LZS],(u32)bufA[c+LZS]));
      v = m;
    }
    bufB[idx]=(u16)v;
  }
  __syncthreads();
  // P2: snapshot E_k center; write E_{k+1} center to global (skipped on last iter)
  int yy0 = tid>>5, xx0 = tid&31;     // 8y x 32x
  u16 ek[TZF];
  #pragma unroll
  for(int j=0;j<TZF;j++){
    ek[j] = bufA[(j+2)*LZS+(yy0+2)*LDX+(xx0+2)];
    if(wimg){
      int n = ((Z0+j)<<14)+((Y0+yy0)<<7)+(X0+xx0);
      vout[n] = bufB[(j+1)*E1S+(yy0+1)*E1X+(xx0+1)];
    }
  }
  __syncthreads();
  // P3: B1[z6][y10][x32] = xmax(E_{k+1}) -> bufA
  for (int idx=tid; idx<B1N; idx+=256){
    int zz=idx/320; int rem=idx-zz*320; int yy=rem>>5; int xx=rem&31;
    int c = zz*E1S+yy*E1X+xx;
    u32 m = max((u32)bufB[c], (u32)bufB[c+1]);
    bufA[idx] = (u16)max(m, (u32)bufB[c+2]);
  }
  __syncthreads();
  // P4: B2[z6][y8][x32] = ymax(B1) -> bufB
  for (int idx=tid; idx<B2N; idx+=256){
    int zz=idx>>8; int rem=idx&255; int yy=rem>>5; int xx=rem&31;
    int c = zz*320+yy*32+xx;
    u32 m = max((u32)bufA[c], (u32)bufA[c+32]);
    bufB[idx] = (u16)max(m, (u32)bufA[c+64]);
  }
  __syncthreads();
  // P5: open = zmax(B2); skel update (fp32 math, fp16 store)
  #pragma unroll
  for(int j=0;j<TZF;j++){
    int c = j*256 + yy0*32 + xx0;
    u32 m = max((u32)bufB[c], (u32)bufB[c+256]);
    m = max(m, (u32)bufB[c+512]);
    float d = fmaxf(h2f(ek[j]) - h2f((u16)m), 0.f);
    int n = ((Z0+j)<<14)+((Y0+yy0)<<7)+(X0+xx0);
    if (INIT) skl[n] = f2h(d);
    else {
      float so = h2f(skl[n]);
      skl[n] = f2h(so + fmaxf(d - so*d, 0.f));
    }
  }
}

// ---------------- systolic fused binary soft-skel iteration (bit-planes) ----------------
__device__ __forceinline__ u64 berode_x(const u64* P, int tid){
  u64 c = P[tid];
  if (tid & 1) return c & ((c<<1)|(P[tid-1]>>63)) & ((c>>1)|(1ull<<63));
  else         return c & ((c<<1)|1ull) & ((c>>1)|(P[tid+1]<<63));
}
__device__ __forceinline__ u64 bdilate_x(const u64* P, int tid){
  u64 c = P[tid];
  if (tid & 1) return c | (c<<1) | (P[tid-1]>>63) | (c>>1);
  else         return c | (c<<1) | (c>>1) | (P[tid+1]<<63);
}

template<bool INIT>
__global__ __launch_bounds__(256) void bskel(const u64* __restrict__ imgin, u64* __restrict__ imgout,
                                             u64* __restrict__ skel)
{
  __shared__ u64 simg[4][256];
  __shared__ u64 se1[6][256];
  __shared__ u64 se2[2][256];
  __shared__ u64 sM[4][256];
  int bid = blockIdx.x;
  int tzb = bid & 15, b = (bid>>4)&1, m = bid>>5;
  int z0 = tzb*4, z1 = z0+4;
  size_t base = (size_t)m*NWORDS + (size_t)b*16384;
  const u64* vin = imgin + base;
  u64* vout = imgout + base;
  u64* skl = skel + base;
  int tid = threadIdx.x;
  int y = tid>>1;

  for (int s = z0-3; s <= z1+6; ++s){
    if (s <= z1+2)
      simg[(s+96)&3][tid] = ((unsigned)s<64u) ? vin[(s<<8)+tid] : ~0ull;
    { int t = s-2;
      if (t >= z0-2 && t <= z1+1){
        u64 r = ~0ull;
        if ((unsigned)t<64u){
          const u64* P = simg[(t+96)&3];
          if (INIT) r = P[tid];
          else {
            r = berode_x(P, tid);
            if(y>0)   r &= P[tid-2];
            if(y<127) r &= P[tid+2];
            r &= simg[(t-1+96)&3][tid] & simg[(t+1+96)&3][tid];
          }
        }
        se1[(t+96)%6][tid] = r;
      }
    }
    { int t = s-4;
      if (t >= z0-1 && t <= z1){
        u64 r = 0;
        if ((unsigned)t<64u){
          const u64* P = se1[(t+96)%6];
          r = berode_x(P, tid);
          if(y>0)   r &= P[tid-2];
          if(y<127) r &= P[tid+2];
          r &= se1[(t-1+96)%6][tid] & se1[(t+1+96)%6][tid];
        }
        se2[(t+96)&1][tid] = r;
      }
    }
    { int t = s-5;
      if (t >= z0-1 && t <= z1){
        const u64* P = se2[(t+96)&1];
        u64 dm = bdilate_x(P, tid);
        if(y>0)   dm |= bdilate_x(P, tid-2);
        if(y<127) dm |= bdilate_x(P, tid+2);
        sM[(t+96)&3][tid] = dm;
      }
    }
    { int z = s-7;
      if (z >= z0 && z < z1){
        u64 open_ = sM[(z-1+96)&3][tid] | sM[(z+96)&3][tid] | sM[(z+1+96)&3][tid];
        u64 e1v = se1[(z+96)%6][tid];
        u64 d = e1v & ~open_;
        int gw = (z<<8)+tid;
        if (INIT) skl[gw] = d;
        else { skl[gw] |= d; vout[gw] = e1v; }
      }
    }
    __syncthreads();
  }
}

// ---------------- separable Chebyshev EDT ----------------
__global__ __launch_bounds__(256) void edt_px(const u64* __restrict__ yb, const u64* __restrict__ hb,
                                              u8* __restrict__ d)
{
  int g = blockIdx.x*256 + threadIdx.x;
  int m = g >> 21;
  int n = g & (NTOT-1);
  const u64* bits = m ? hb : yb;
  int x = n & 127;
  int row = n >> 7;
  u64 w0 = bits[row*2], w1 = bits[row*2+1];
  int a = x - 31;
  u64 win;
  if (a < 0)        win = w0 << (-a);
  else if (a == 0)  win = w0;
  else if (a < 64)  win = (w0 >> a) | (w1 << (64-a));
  else              win = w1 >> (a-64);
  if (x < 31)  win |= (1ull << (31-x)) - 1;
  if (x > 95)  win |= (~0ull) << (159-x);
  u64 inv = ~win;
  u64 tl = inv & 0xFFFFFFFFull;
  u64 tr = inv >> 31;
  int dl = tl ? (31 - (63 - __clzll(tl))) : 99;
  int dr = tr ? (__ffsll((unsigned long long)tr) - 1) : 99;
  int dd = min(min(dl, dr), 16);
  d[(size_t)m*NTOT + n] = (u8)dd;
}

__global__ __launch_bounds__(256) void edt_py(const u8* __restrict__ din, u8* __restrict__ dout){
  int g = blockIdx.x*256 + threadIdx.x;
  int n = g & (NTOT-1);
  int c = (n >> 7) & 127;
  size_t idx = (size_t)(g>>21)*NTOT + n;
  int best = din[idx];
  #pragma unroll 4
  for (int k=1; k<=16; ++k){
    if (best <= k) break;
    int v = 255;
    if (c-k >= 0)   v = din[idx - (size_t)k*128];
    if (c+k < 128)  v = min(v, (int)din[idx + (size_t)k*128]);
    best = min(best, max(k, v));
  }
  dout[idx] = (u8)best;
}

// z-pass + per-block skeleton-radius max/min partials
__global__ __launch_bounds__(256) void edt_pz_part(const u8* __restrict__ din, u8* __restrict__ dout,
    const u64* __restrict__ skel2, const u64* __restrict__ hbits,
    u8* __restrict__ pmax, u8* __restrict__ pmin)
{
  int tid = threadIdx.x;
  int g = blockIdx.x*256 + tid;
  int m = g >> 21;
  int n = g & (NTOT-1);
  int c = (n >> 14) & 63;
  size_t idx = (size_t)m*NTOT + n;
  int best = din[idx];
  #pragma unroll 4
  for (int k=1; k<=16; ++k){
    if (best <= k) break;
    int v = 255;
    if (c-k >= 0)  v = din[idx - (size_t)k*16384];
    if (c+k < 64)  v = min(v, (int)din[idx + (size_t)k*16384]);
    best = min(best, max(k, v));
  }
  dout[idx] = (u8)best;
  int wi = n>>6, bit = n&63;
  u64 sbit = m ? (skel2[NWORDS+wi] & hbits[wi]) : skel2[wi];
  u32 r = (u32)((sbit>>bit)&1ull) ? (u32)best : 0u;
  __shared__ u32 sx[256], sn_[256];
  sx[tid]=r; sn_[tid]=r;
  __syncthreads();
  for(int s=128;s>0;s>>=1){
    if(tid<s){
      if(sx[tid+s]>sx[tid]) sx[tid]=sx[tid+s];
      if(sn_[tid+s]<sn_[tid]) sn_[tid]=sn_[tid+s];
    }
    __syncthreads();
  }
  if(tid==0){ pmax[blockIdx.x]=(u8)sx[0]; pmin[blockIdx.x]=(u8)sn_[0]; }
}

// reduce 16384 block partials -> mm[8]
__global__ __launch_bounds__(256) void rmm2(const u8* __restrict__ pmax, const u8* __restrict__ pmin,
                                            u32* __restrict__ mm){
  __shared__ u8 smx[4][256], smn[4][256];
  int tid = threadIdx.x;
  u8 mx[4]={0,0,0,0}, mn[4]={255,255,255,255};
  for(int i=tid;i<16384;i+=256){
    int sel=i>>13, b=(i>>12)&1, cc=sel*2+b;
    u8 a=pmax[i], d=pmin[i];
    if(a>mx[cc]) mx[cc]=a;
    if(d<mn[cc]) mn[cc]=d;
  }
  #pragma unroll
  for(int cc=0;cc<4;cc++){ smx[cc][tid]=mx[cc]; smn[cc][tid]=mn[cc]; }
  __syncthreads();
  for(int s=128;s>0;s>>=1){
    if(tid<s){
      #pragma unroll
      for(int cc=0;cc<4;cc++){
        if(smx[cc][tid+s]>smx[cc][tid]) smx[cc][tid]=smx[cc][tid+s];
        if(smn[cc][tid+s]<smn[cc][tid]) smn[cc][tid]=smn[cc][tid+s];
      }
    }
    __syncthreads();
  }
  if(tid==0){
    #pragma unroll
    for(int cc=0;cc<4;cc++){
      int sel=cc>>1, b=cc&1;
      mm[sel*4+b]   = (u32)smx[cc][0];
      mm[sel*4+2+b] = (u32)smn[cc][0];
    }
  }
}

// ---------------- fused sobel + final reduce, 4 voxels per thread ----------------
__global__ __launch_bounds__(256) void k_tail(const float* __restrict__ net, const u16* __restrict__ skelp,
    const u64* __restrict__ ybits, const u64* __restrict__ hbits, const u64* __restrict__ skel2,
    const u8* __restrict__ acc, const u8* __restrict__ y8, const u32* __restrict__ mm,
    double* __restrict__ part1)
{
  float rmaxT_[2], rminT_[2], rmaxH_[2], rminH_[2];
  for(int b=0;b<2;b++){
    rmaxT_[b]=fmaxf((float)mm[b],1.f);   rminT_[b]=fmaxf((float)mm[2+b],1.f);
    rmaxH_[b]=fmaxf((float)mm[4+b],1.f); rminH_[b]=fmaxf((float)mm[6+b],1.f);
  }
  const int SMi[3]={1,2,1}, DVi[3]={-1,0,1};
  int r = blockIdx.x*256 + threadIdx.x;   // exactly NTOT/4 threads
  int n0 = r<<2;
  int b = n0>>20, v0 = n0&(VOL-1);
  int xb = n0&127, y=(n0>>7)&127, z=(n0>>14)&63;
  const float* P = net + (size_t)b*(2*VOL);
  const u8* Y8 = y8 + ((size_t)b<<20);
  float gpx[4]={0,0,0,0}, gpy[4]={0,0,0,0}, gpz[4]={0,0,0,0};
  int   gtx[4]={0,0,0,0}, gty[4]={0,0,0,0}, gtz[4]={0,0,0,0};
  #pragma unroll
  for(int da=0;da<3;da++){
    int zz=z+da-1; if((unsigned)zz>=64u) continue;
    #pragma unroll
    for(int db=0;db<3;db++){
      int yy=y+db-1; if((unsigned)yy>=128u) continue;
      int rb_ = (zz<<14)+(yy<<7)+xb;
      float pv[6]; int tv[6];
      #pragma unroll
      for(int j=0;j<6;j++){
        int xx = xb-1+j;
        bool ok = (unsigned)xx<128u;
        pv[j] = ok ? P[rb_-1+j] : 0.f;
        tv[j] = ok ? (int)Y8[rb_-1+j] : 0;
      }
      int smb=SMi[db], sma=SMi[da], dva=DVi[da];
      #pragma unroll
      for(int e=0;e<4;e++){
        float ep = pv[e+2]-pv[e], sp = pv[e]+2.f*pv[e+1]+pv[e+2];
        gpx[e] += (float)smb*ep; gpy[e] += (float)sma*ep; gpz[e] += (float)dva*sp;
        int et = tv[e+2]-tv[e], st = tv[e]+2*tv[e+1]+tv[e+2];
        gtx[e] += smb*et; gty[e] += sma*et; gtz[e] += dva*st;
      }
    }
  }
  float4 X0 = *(const float4*)&P[v0];
  float4 X1 = *(const float4*)&P[VOL+v0];
  ushort4 SK = *(const ushort4*)&skelp[n0];
  uchar4 DT = *(const uchar4*)&acc[n0];
  uchar4 DH = *(const uchar4*)&acc[NTOT+n0];
  int wi0 = n0>>6, bit0 = n0&63;
  int ybq = (int)((ybits[wi0]>>bit0)&0xFull);
  int hdq = (int)((hbits[wi0]>>bit0)&0xFull);
  int sTq = (int)((skel2[wi0]>>bit0)&0xFull);
  int sHq = (int)((skel2[NWORDS+wi0]>>bit0)&0xFull);
  float fsob=0,fcl1=0,fcl2=0,fcl3=0,fcl4=0,fi1=0,fun1=0,fi2=0,fun2=0;
  #pragma unroll
  for(int e=0;e<4;e++){
    float ftx=(float)gtx[e], fty=(float)gty[e], ftz=(float)gtz[e];
    float np_=sqrtf(gpx[e]*gpx[e]+gpy[e]*gpy[e]+gpz[e]*gpz[e]);
    float nt_=sqrtf(ftx*ftx+fty*fty+ftz*ftz);
    float ip=1.f/fmaxf(np_,1e-12f), it=1.f/fmaxf(nt_,1e-12f);
    float num=(gpx[e]*ftx+gpy[e]*fty+gpz[e]*ftz)*ip*it;
    float den=fmaxf((np_*ip)*(nt_*it),1e-8f);
    fsob += num/den;
    int yb=(ybq>>e)&1, hd=(hdq>>e)&1, sT=(sTq>>e)&1, sH=(sHq>>e)&1;
    float dT=(float)((const u8*)&DT)[e], dH=(float)((const u8*)&DH)[e];
    float x0v=((const float*)&X0)[e], x1v=((const float*)&X1)[e];
    float p = 1.f/(1.f+__expf(x0v-x1v));
    float sk = h2f(((const u16*)&SK)[e]);
    fcl1 += sk*(float)yb;
    fcl2 += sk;
    float q_vl = yb ? fminf(dT,rmaxT_[b])/rmaxT_[b] : 0.f;
    if (sT){
      fcl3 += p; fcl4 += 1.f;
      float t=(rmaxT_[b]-dT+rminT_[b])/rmaxT_[b]; float q_sl=t*t;
      float q_vp = fminf(dH,rmaxH_[b])/rmaxH_[b]*p;
      fi2  += q_sl*__powf(q_vp+1e-4f,0.7f)*q_sl;
      fun2 += q_sl*(0.1f*q_vp+0.9f*q_sl);
    }
    if (sH & hd){
      float t=(rmaxH_[b]-dH+rminH_[b])/rmaxH_[b]; float q_sp=t*t*p;
      fi1  += q_sp*__powf(q_sp+1e-4f,0.7f)*q_vl;
      fun1 += q_sp*(0.1f*q_sp+0.9f*q_vl);
    }
  }
  __shared__ double sw[9][4];
  int wid = threadIdx.x>>6, lane = threadIdx.x&63;
  double vals[9] = {fsob,fcl1,fcl2,fcl3,fcl4,fi1,fun1,fi2,fun2};
  #pragma unroll
  for(int s=0;s<9;s++){ double rr = wred(vals[s]); if(lane==0) sw[s][wid]=rr; }
  __syncthreads();
  if(threadIdx.x==0){
    #pragma unroll
    for(int s=0;s<9;s++) part1[(size_t)s*PC1 + blockIdx.x] = sw[s][0]+sw[s][1]+sw[s][2]+sw[s][3];
  }
}

// ---------------- two-stage finalize ----------------
__global__ __launch_bounds__(256) void k_reduce_mid(const double* __restrict__ part0,
                                                    const double* __restrict__ part1,
                                                    double* __restrict__ tot){
  int s = blockIdx.x;  // 0..13
  const double* src; int n;
  if (s < 5){ src = part0 + (size_t)s*PC0; n = PC0; }
  else      { src = part1 + (size_t)(s-5)*PC1; n = PC1; }
  double v=0;
  for(int i=threadIdx.x;i<n;i+=256) v += src[i];
  __shared__ double sd[256];
  sd[threadIdx.x]=v; __syncthreads();
  for(int k=128;k>0;k>>=1){ if((int)threadIdx.x<k) sd[threadIdx.x]+=sd[threadIdx.x+k]; __syncthreads(); }
  if(threadIdx.x==0) tot[s]=sd[0];
}

__global__ void k_fin(const double* __restrict__ tot, float* __restrict__ out){
  if(threadIdx.x==0 && blockIdx.x==0){
    const double N = (double)NTOT;
    double ce = tot[0]/N;
    double tp=tot[1], fp=tot[2]-tot[1], fn=tot[3]-tot[1];
    double dice = -((2.0*tp+1e-5)/(2.0*tp+fp+fn+1e-5));
    double conn = tot[4]/(2.0*N);
    double dir  = 1.0 - tot[5]/N;
    double tprec = (tot[6]+1.0)/(tot[7]+1.0);
    double tsens = (tot[8]+1.0)/(tot[9]+1.0);
    double cld = 1.0 - 2.0*tprec*tsens/(tprec+tsens);
    double u1 = 1.0 - (tot[10]+1.0)/(tot[11]+1.0);
    double u2 = 1.0 - (tot[12]+1.0)/(tot[13]+1.0);
    out[0] = (float)(dice+ce+cld+dir+conn+u1+u2);
  }
}

extern "C" void kernel_launch(void* const* d_in, const int* in_sizes, int n_in,
                              void* d_out, int out_size, void* d_ws, size_t ws_size,
                              hipStream_t stream)
{
  (void)in_sizes; (void)n_in; (void)out_size; (void)ws_size;
  const float* net = (const float*)d_in[0];
  const int*   tgt = (const int*)d_in[1];
  float* out = (float*)d_out;
  char* w = (char*)d_ws;
  const size_t MB = 1024*1024;
  u16* F1 = (u16*)(w + 0*MB);              // prob img ping (fp16, 4 MB)
  u16* F2 = (u16*)(w + 4*MB);              // skel_pred (fp16, 4 MB)
  u16* F3 = (u16*)(w + 8*MB);              // img pong (fp16, 4 MB)
  u64* ybits = (u64*)(w + 12*MB);
  u64* hbits = ybits + NWORDS;
  u64* skel2 = hbits + NWORDS;             // [T][H]
  u64* bping = skel2 + 2*NWORDS;           // [T][H]
  u64* bpong = bping + 2*NWORDS;
  u8*  dA    = (u8*)(bpong + 2*NWORDS);    // 4 MB
  u8*  dB    = dA + (size_t)2*NTOT;        // 4 MB
  u8*  y8    = dB + (size_t)2*NTOT;        // 2 MB
  double* part0 = (double*)(y8 + (size_t)NTOT);
  double* part1 = part0 + (size_t)5*PC0;
  double* tot   = part1 + (size_t)9*PC1;
  u8* pmax = (u8*)(tot + 16);
  u8* pmin = pmax + 16384;
  u32* mm  = (u32*)(pmin + 16384);

  k_init<<<PC0, 256, 0, stream>>>(net, tgt, F1, ybits, hbits, bping, y8, part0);

  // binary soft_skel for y_true and hard: 11 systolic dispatches (64 blocks each)
  bskel<true><<<64,256,0,stream>>>(bping, bpong, skel2);
  {
    u64* pi=bping; u64* po=bpong;
    for(int i=0;i<10;i++){ bskel<false><<<64,256,0,stream>>>(pi,po,skel2); u64* t=pi; pi=po; po=t; }
  }

  // float soft_skel(prob, 10): 11 fp16 tile dispatches, 2048 blocks each
  fskel<true><<<2048,256,0,stream>>>(F1, F3, F2, 1);
  {
    u16* pi=F3; u16* po=F1;
    for(int i=0;i<10;i++){
      fskel<false><<<2048,256,0,stream>>>(pi,po,F2, (i<9)?1:0);
      u16* t=pi; pi=po; po=t;
    }
  }

  // separable Chebyshev EDT (+ fused skeleton-radius partials in z-pass)
  const int GE = (2*NTOT)/256;
  edt_px<<<GE,256,0,stream>>>(ybits, hbits, dA);
  edt_py<<<GE,256,0,stream>>>(dA, dB);
  edt_pz_part<<<GE,256,0,stream>>>(dB, dA, skel2, hbits, pmax, pmin);
  rmm2<<<1,256,0,stream>>>(pmax, pmin, mm);

  k_tail<<<PC1,256,0,stream>>>(net, F2, ybits, hbits, skel2, dA, y8, mm, part1);
  k_reduce_mid<<<14,256,0,stream>>>(part0, part1, tot);
  k_fin<<<1,64,0,stream>>>(tot, out);
}